// Round 3
// baseline (323.494 us; speedup 1.0000x reference)
//
#include <hip/hip_runtime.h>

using bf16x8 = __attribute__((ext_vector_type(8))) short;
using f32x4  = __attribute__((ext_vector_type(4))) float;

#define B_  2
#define T_  2048
#define C_  2048
#define H_  16
#define KV_ 4
#define D_  128

__device__ __forceinline__ unsigned short f2b(float f) {
  union { float f; unsigned int u; } v; v.f = f;
  unsigned int r = v.u + 0x7fffu + ((v.u >> 16) & 1u);   // RTNE
  return (unsigned short)(r >> 16);
}
__device__ __forceinline__ float b2f(unsigned short u) {
  union { unsigned int u; float f; } v; v.u = ((unsigned int)u) << 16;
  return v.f;
}
// packed f32x2 -> bf16x2 (RTNE), single VALU op (no gfx950 builtin; T12 recipe)
__device__ __forceinline__ unsigned int cvt_pk_bf16(float lo, float hi) {
  unsigned int r;
  asm("v_cvt_pk_bf16_f32 %0, %1, %2" : "=v"(r) : "v"(lo), "v"(hi));
  return r;
}
// async global->LDS, 16B per lane; LDS dest must be lane-contiguous (wave base + lane*16)
__device__ __forceinline__ void gld_lds16(const void* g, void* l) {
  __builtin_amdgcn_global_load_lds(
      (__attribute__((address_space(1))) void*)g,
      (__attribute__((address_space(3))) void*)l, 16, 0, 0);
}

// ---------------- elementwise cast x -> bf16 ----------------
__global__ void cast_bf16_k(const float* __restrict__ in, unsigned short* __restrict__ out) {
  int i = blockIdx.x * 256 + threadIdx.x;
  float4 f = ((const float4*)in)[i];
  ushort4 u; u.x = f2b(f.x); u.y = f2b(f.y); u.z = f2b(f.z); u.w = f2b(f.w);
  ((ushort4*)out)[i] = u;
}

// ---------------- transpose-cast W (K x N fp32) -> Wt (N x K bf16) ----------------
__global__ void wtrans(const float* __restrict__ W, unsigned short* __restrict__ Wt,
                       int K, int N) {
  __shared__ float s[32][33];
  int n0 = blockIdx.x * 32, k0 = blockIdx.y * 32;
  int tx = threadIdx.x, ty = threadIdx.y;
  #pragma unroll
  for (int yy = 0; yy < 32; yy += 8)
    s[ty + yy][tx] = W[(size_t)(k0 + ty + yy) * N + n0 + tx];
  __syncthreads();
  #pragma unroll
  for (int yy = 0; yy < 32; yy += 8)
    Wt[(size_t)(n0 + ty + yy) * K + k0 + tx] = f2b(s[tx][ty + yy]);
}

// ---------------- m97-style bf16 MFMA GEMM tile: C = A(MxK) * Bt(NxK)^T ----------------
// (kept for out_gemm; qkv moved to the 8-phase 256^2 kernel below)
template <bool OUT_BF16>
__device__ __forceinline__ void gemm_tile(
    const unsigned short* __restrict__ A, const unsigned short* __restrict__ Bt,
    void* __restrict__ Cv, int K, int ldc, int m0, int n0b, int n0c,
    unsigned short* sA, unsigned short* sB)
{
  const int tid  = threadIdx.x;
  const int lane = tid & 63, w = tid >> 6;
  const int quad = lane >> 4, l16 = lane & 15;
  const int wm = (w >> 1) * 64, wn = (w & 1) * 64;

  f32x4 acc[4][4] = {};

  const unsigned short* Abase = A  + (size_t)m0  * K;
  const unsigned short* Bbase = Bt + (size_t)n0b * K;

  for (int k0 = 0; k0 < K; k0 += 32) {
    #pragma unroll
    for (int r = 0; r < 2; ++r) {                   // 128x32 bf16 tile = 512 chunks of 16B
      int c = tid + r * 256;
      int row = c >> 2, col = (c & 3) * 8;
      gld_lds16(Abase + (size_t)row * K + k0 + col, sA + c * 8);
      gld_lds16(Bbase + (size_t)row * K + k0 + col, sB + c * 8);
    }
    __syncthreads();                                // drains vmcnt, LDS visible
    bf16x8 af[4], bfr[4];
    #pragma unroll
    for (int i = 0; i < 4; ++i)
      af[i]  = *(const bf16x8*)(sA + (wm + i * 16 + l16) * 32 + quad * 8);
    #pragma unroll
    for (int j = 0; j < 4; ++j)
      bfr[j] = *(const bf16x8*)(sB + (wn + j * 16 + l16) * 32 + quad * 8);
    #pragma unroll
    for (int i = 0; i < 4; ++i)
      #pragma unroll
      for (int j = 0; j < 4; ++j)
        acc[i][j] = __builtin_amdgcn_mfma_f32_16x16x32_bf16(af[i], bfr[j], acc[i][j], 0, 0, 0);
    __syncthreads();                                // all waves done reading before overwrite
  }
  #pragma unroll
  for (int i = 0; i < 4; ++i) {
    #pragma unroll
    for (int r = 0; r < 4; ++r) {
      int row = m0 + wm + i * 16 + quad * 4 + r;    // C/D: row = quad*4+reg, col = lane&15
      #pragma unroll
      for (int j = 0; j < 4; ++j) {
        int col = n0c + wn + j * 16 + l16;
        float v = acc[i][j][r];
        if (OUT_BF16) ((unsigned short*)Cv)[(size_t)row * ldc + col] = f2b(v);
        else          ((float*)Cv)[(size_t)row * ldc + col] = v;
      }
    }
  }
}

__global__ void out_gemm(const unsigned short* __restrict__ yb,
                         const unsigned short* __restrict__ Wot,
                         float* __restrict__ out) {
  __shared__ unsigned short sA[128 * 32], sB[128 * 32];
  gemm_tile<false>(yb, Wot, out, C_, C_, blockIdx.y * 128, blockIdx.x * 128, blockIdx.x * 128,
                   sA, sB);
}

// ---------------- qkv GEMM, 256^2-tile 8-phase schedule (T2+T3+T4+T5) ----------------
// v8 evidence: qkv at 70.8us = 728 TF = m97 2-barrier structure ceiling; MfmaUtil 30%,
// VALU 14%, HBM 17% -> critical path is stage+vmcnt(0)+barrier (m233: ~72% overhead).
// This kernel: BM=BN=256, BK=64 (2 K-halves), 8 waves (2Mx4N, 128x64 out each),
// 128 KiB LDS double-buffer. Per K-tile 4 phases: {ds_read frags | stage 1 half-tile |
// barrier | lgkmcnt(0) | setprio(1) 16xMFMA setprio(0) | [vmcnt(4)] barrier}.
// Counted vmcnt(4) twice per tile (staging order A-K0,B-K0,A-K1,B-K1 => at each wait
// exactly 8 own loads outstanding, oldest 4 = the halves needed next; never drain to 0).
// LDS XOR-swizzle col ^= ((row>>2)&3)<<3 (16B-chunk granular): read pattern spreads
// 16 lanes across 8 bank groups (2-way = free, m136) vs 8-way unswizzled. Applied
// both-sides (rule #21): linear LDS dest, inverse-swizzled GLOBAL source, swizzled read.
// Grid 192 = 16 mt x 12 nt; XCD-striped: XCD x owns mt {2x,2x+1} (A panels 2MB in L2).
__global__ __launch_bounds__(512, 2) void qkv_gemm8(
    const unsigned short* __restrict__ xb,
    const unsigned short* __restrict__ Wqt,
    const unsigned short* __restrict__ Wkt,
    const unsigned short* __restrict__ Wvt,
    unsigned short* __restrict__ q, unsigned short* __restrict__ k,
    unsigned short* __restrict__ v) {
  __shared__ unsigned short lds[65536];   // A: [2buf][2kh][256*32] ; B same at +32768

  const int id  = (int)blockIdx.x;        // 0..191; id&7 = XCD (round-robin dispatch)
  const int xcd = id & 7, jj = id >> 3;   // 24 blocks per XCD
  const int mt  = xcd * 2 + jj / 12;
  const int nt  = jj % 12;

  const unsigned short* Bt; unsigned short* Cp; int n0, ldc;
  if (nt < 8)       { Bt = Wqt; Cp = q; n0 = nt * 256;        ldc = 2048; }
  else if (nt < 10) { Bt = Wkt; Cp = k; n0 = (nt - 8) * 256;  ldc = 512;  }
  else              { Bt = Wvt; Cp = v; n0 = (nt - 10) * 256; ldc = 512;  }
  const int m0 = mt * 256;

  const int tid = (int)threadIdx.x;
  const int w = tid >> 6, lane = tid & 63;
  const int quad = lane >> 4, l16 = lane & 15;
  const int wr = w >> 2, wc = w & 3;             // wave tile: rows wr*128, cols wc*64
  const int swz = (l16 & 12) << 1;               // ((row>>2)&3)<<3 with row=...+l16

  const unsigned short* Ab = xb + (size_t)m0 * 2048;
  const unsigned short* Bb = Bt + (size_t)n0 * 2048;

  // staging chunk geometry: 1024 chunks x 16B per half-tile (256 rows x 32 shorts)
  const int c0 = tid, c1 = tid + 512;
  const int r0 = c0 >> 2, r1 = c1 >> 2;
  const int x0 = ((c0 & 3) * 8) ^ (((c0 >> 4) & 3) << 3);   // inverse-swizzled src col
  const int x1 = ((c1 & 3) * 8) ^ (((c1 >> 4) & 3) << 3);

#define STAGE_A(buf, kh, kb) do { \
    unsigned short* d_ = lds + (buf) * 16384 + (kh) * 8192; \
    gld_lds16(Ab + (size_t)r0 * 2048 + (kb) + (kh) * 32 + x0, d_ + c0 * 8); \
    gld_lds16(Ab + (size_t)r1 * 2048 + (kb) + (kh) * 32 + x1, d_ + c1 * 8); \
  } while (0)
#define STAGE_B(buf, kh, kb) do { \
    unsigned short* d_ = lds + 32768 + (buf) * 16384 + (kh) * 8192; \
    gld_lds16(Bb + (size_t)r0 * 2048 + (kb) + (kh) * 32 + x0, d_ + c0 * 8); \
    gld_lds16(Bb + (size_t)r1 * 2048 + (kb) + (kh) * 32 + x1, d_ + c1 * 8); \
  } while (0)

  f32x4 acc[8][4] = {};

  // prologue: stage tile 0 (A-K0, B-K0, A-K1, B-K1); wait K0 halves; barrier
  STAGE_A(0, 0, 0); STAGE_B(0, 0, 0); STAGE_A(0, 1, 0); STAGE_B(0, 1, 0);
  asm volatile("s_waitcnt vmcnt(4)" ::: "memory");
  __builtin_amdgcn_s_barrier();

  const unsigned short* aLd = lds + (wr * 128 + l16) * 32 + (quad * 8 ^ swz);
  const unsigned short* bLd = lds + 32768 + (wc * 64 + l16) * 32 + (quad * 8 ^ swz);

  for (int t = 0; t < 32; ++t) {
    const int cur = t & 1, nxt = cur ^ 1;
    const bool more = (t < 31);
    const int kb = (t + 1) * 64;
    const int off = cur * 16384;
    bf16x8 a[8], bbr[4];

    // ---- phase 0: read ks0 frags; stage A-K0(t+1); MFMA ks0 m0-3 ----
    #pragma unroll
    for (int m = 0; m < 8; ++m) a[m] = *(const bf16x8*)(aLd + off + m * 512);
    #pragma unroll
    for (int n = 0; n < 4; ++n) bbr[n] = *(const bf16x8*)(bLd + off + n * 512);
    if (more) STAGE_A(nxt, 0, kb);
    __builtin_amdgcn_s_barrier();
    asm volatile("s_waitcnt lgkmcnt(0)" ::: "memory");
    __builtin_amdgcn_sched_barrier(0);
    __builtin_amdgcn_s_setprio(1);
    #pragma unroll
    for (int m = 0; m < 4; ++m)
      #pragma unroll
      for (int n = 0; n < 4; ++n)
        acc[m][n] = __builtin_amdgcn_mfma_f32_16x16x32_bf16(a[m], bbr[n], acc[m][n], 0, 0, 0);
    __builtin_amdgcn_s_setprio(0);
    __builtin_amdgcn_s_barrier();

    // ---- phase 1: stage B-K0(t+1); MFMA ks0 m4-7; vmcnt(4) ----
    if (more) STAGE_B(nxt, 0, kb);
    __builtin_amdgcn_s_barrier();
    __builtin_amdgcn_s_setprio(1);
    #pragma unroll
    for (int m = 4; m < 8; ++m)
      #pragma unroll
      for (int n = 0; n < 4; ++n)
        acc[m][n] = __builtin_amdgcn_mfma_f32_16x16x32_bf16(a[m], bbr[n], acc[m][n], 0, 0, 0);
    __builtin_amdgcn_s_setprio(0);
    if (more) asm volatile("s_waitcnt vmcnt(4)" ::: "memory");
    else      asm volatile("s_waitcnt vmcnt(0)" ::: "memory");
    __builtin_amdgcn_s_barrier();

    // ---- phase 2: read ks1 frags; stage A-K1(t+1); MFMA ks1 m0-3 ----
    #pragma unroll
    for (int m = 0; m < 8; ++m) a[m] = *(const bf16x8*)(aLd + off + 8192 + m * 512);
    #pragma unroll
    for (int n = 0; n < 4; ++n) bbr[n] = *(const bf16x8*)(bLd + off + 8192 + n * 512);
    if (more) STAGE_A(nxt, 1, kb);
    __builtin_amdgcn_s_barrier();
    asm volatile("s_waitcnt lgkmcnt(0)" ::: "memory");
    __builtin_amdgcn_sched_barrier(0);
    __builtin_amdgcn_s_setprio(1);
    #pragma unroll
    for (int m = 0; m < 4; ++m)
      #pragma unroll
      for (int n = 0; n < 4; ++n)
        acc[m][n] = __builtin_amdgcn_mfma_f32_16x16x32_bf16(a[m], bbr[n], acc[m][n], 0, 0, 0);
    __builtin_amdgcn_s_setprio(0);
    __builtin_amdgcn_s_barrier();

    // ---- phase 3: stage B-K1(t+1); MFMA ks1 m4-7; vmcnt(4) ----
    if (more) STAGE_B(nxt, 1, kb);
    __builtin_amdgcn_s_barrier();
    __builtin_amdgcn_s_setprio(1);
    #pragma unroll
    for (int m = 4; m < 8; ++m)
      #pragma unroll
      for (int n = 0; n < 4; ++n)
        acc[m][n] = __builtin_amdgcn_mfma_f32_16x16x32_bf16(a[m], bbr[n], acc[m][n], 0, 0, 0);
    __builtin_amdgcn_s_setprio(0);
    if (more) asm volatile("s_waitcnt vmcnt(4)" ::: "memory");
    else      asm volatile("s_waitcnt vmcnt(0)" ::: "memory");
    __builtin_amdgcn_s_barrier();
  }
#undef STAGE_A
#undef STAGE_B

  // epilogue: C-layout row = quad*4+reg, col = l16
  #pragma unroll
  for (int m = 0; m < 8; ++m)
    #pragma unroll
    for (int r = 0; r < 4; ++r) {
      int row = m0 + wr * 128 + m * 16 + quad * 4 + r;
      #pragma unroll
      for (int n = 0; n < 4; ++n) {
        int col = n0 + wc * 64 + n * 16 + l16;
        Cp[(size_t)row * ldc + col] = f2b(acc[m][n][r]);
      }
    }
}

// ---------------- RoPE + RMSNorm -> MFMA-fragment-order output ----------------
// per (b,head): [t16 (128 tiles)][f = d>>3 (16)][t&15 (16)][d&7 (8)]  (tile = 2048 shorts)
template <int NH>
__global__ void ropenorm(const unsigned short* __restrict__ in,
                         const float* __restrict__ cs, const float* __restrict__ sn,
                         unsigned short* __restrict__ out, float oscale) {
  int row  = blockIdx.x * 4 + (threadIdx.x >> 6);
  int lane = threadIdx.x & 63;
  int head = row % NH;
  int t = (row / NH) & (T_ - 1);
  int b = row / (NH * T_);
  const unsigned short* p = in + (size_t)row * D_;
  float t1 = b2f(p[lane]), t2 = b2f(p[lane + 64]);
  float c = cs[t * 64 + lane], s = sn[t * 64 + lane];
  float o1 = t1 * c + t2 * s;
  float o2 = t2 * c - t1 * s;
  float ss = o1 * o1 + o2 * o2;
  #pragma unroll
  for (int off = 32; off > 0; off >>= 1) ss += __shfl_xor(ss, off, 64);
  float r = rsqrtf(ss * (1.0f / 128.0f) + 1.1920929e-07f) * oscale;
  size_t base = ((size_t)((b * NH + head) * 128 + (t >> 4))) * 2048 + (size_t)(t & 15) * 8;
  out[base + (size_t)(lane >> 3) * 128 + (lane & 7)]       = f2b(o1 * r);
  out[base + (size_t)(8 + (lane >> 3)) * 128 + (lane & 7)] = f2b(o2 * r);
}

// ---------------- V repack: (B,T,KV,D) bf16 -> fragment order for PV B-operand ---------
// per (b,kv): [it (32 tiles of 64 t)][dt = d>>4 (8)][f = (t&63)>>3 (8)][d&15 (16)][t&7 (8)]
__global__ void vfrag_k(const unsigned short* __restrict__ v, unsigned short* __restrict__ vf) {
  int it = blockIdx.x;
  int b = blockIdx.y >> 2, kv = blockIdx.y & 3;
  int d = threadIdx.x, ty = threadIdx.y;
  int t0 = it * 64;
  size_t obase = ((size_t)((b * KV_ + kv) * 32 + it)) * 8192
               + (size_t)(d >> 4) * 1024 + (size_t)(d & 15) * 8;
  #pragma unroll
  for (int tcg = 0; tcg < 4; ++tcg) {
    int tc = ty * 4 + tcg;                   // f chunk 0..7
    unsigned short val[8];
    #pragma unroll
    for (int e = 0; e < 8; ++e)              // coalesced: 128 lanes contiguous in d
      val[e] = v[(((size_t)(b * T_) + t0 + tc * 8 + e) * KV_ + kv) * D_ + d];
    ushort4 u0 = {val[0], val[1], val[2], val[3]};
    ushort4 u1 = {val[4], val[5], val[6], val[7]};
    *(ushort4*)(vf + obase + (size_t)tc * 128)     = u0;
    *(ushort4*)(vf + obase + (size_t)tc * 128 + 4) = u1;
  }
}

// ---------------- flash attention v8: kv-split 2x, static-max softmax ----------------
// Block = 4 waves: w = qsel + 2*half; qsel picks qt in {j,63-j} (uniform block work);
// each wave does kv tiles it = half, half+2, ... and halves merge once via LDS
// (static max M=12 makes the combine LINEAR: o = o_a+o_b, l = l_a+l_b, no rescale).
// grid(8,128): linearId%8 = b*4+kv -> each (b,kv)'s K/V stays on one XCD's L2.
__global__ __launch_bounds__(256, 2) void attn_kernel(
    const unsigned short* __restrict__ qf, const unsigned short* __restrict__ kf,
    const unsigned short* __restrict__ vf, unsigned short* __restrict__ yb) {
  // P: 4 waves x 32x72 shorts = 18432B, dead after loop;
  // reused as combine buf: 2 pairs x (32x132 f32 o + 32 f32 l) = 34048B
  __shared__ __align__(16) char smem[34048];

  const int xp = (int)blockIdx.x;              // 0..7 = b*4+kv  (XCD swizzle)
  const int b = xp >> 2, kv = xp & 3;
  const int yp = (int)blockIdx.y;              // 0..127
  const int j = yp >> 2, hp = yp & 3;
  const int tid = threadIdx.x;
  const int w = tid >> 6, lane = tid & 63;
  const int quad = lane >> 4, l16 = lane & 15;
  const int qsel = w & 1, half = w >> 1;
  const int qt = qsel ? (63 - j) : j;          // paired lengths: block total constant
  const int h = kv * 4 + hp;
  const int q0 = qt * 32;
  const int ntile = (qt >> 1) + 1;
  unsigned short* myP = (unsigned short*)smem + w * (32 * 72);

  const unsigned short* Qf = qf + ((size_t)(b * H_ + h) * 128 + qt * 2) * 2048;
  const unsigned short* Kf = kf + (size_t)(b * KV_ + kv) * 128 * 2048;
  const unsigned short* Vf = vf + (size_t)(b * KV_ + kv) * 32 * 8192;

  // persistent Q fragments (B-operand: n = q row, k = head dim), frag-order (coalesced)
  bf16x8 bq[2][4];
  #pragma unroll
  for (int i = 0; i < 2; ++i)
    #pragma unroll
    for (int kk = 0; kk < 4; ++kk)
      bq[i][kk] = *(const bf16x8*)(Qf + (size_t)i * 2048 + (kk * 4 + quad) * 128 + l16 * 8);

  float l_i[2] = {0.f, 0.f};                   // per-lane partial sum (q = l16 within tile i)
  f32x4 o[2][8] = {};                          // rows q (C-layout), cols d

  for (int it = half; it < ntile; it += 2) {   // this wave's half of the kv tiles
    const int t0 = it * 64;
    const unsigned short* Kt = Kf + (size_t)(it * 4) * 2048;
    const unsigned short* Vt = Vf + (size_t)it * 8192;

    // S^T = K Q^T : 64 k rows (4 tiles) x 32 q cols (2 tiles)
    f32x4 sc[4][2] = {};
    #pragma unroll
    for (int kk = 0; kk < 4; ++kk) {
      bf16x8 ak[4];
      #pragma unroll
      for (int jt = 0; jt < 4; ++jt)
        ak[jt] = *(const bf16x8*)(Kt + (size_t)jt * 2048 + (kk * 4 + quad) * 128 + l16 * 8);
      #pragma unroll
      for (int jt = 0; jt < 4; ++jt)
        #pragma unroll
        for (int i = 0; i < 2; ++i)
          sc[jt][i] = __builtin_amdgcn_mfma_f32_16x16x32_bf16(ak[jt], bq[i][kk], sc[jt][i], 0, 0, 0);
    }

    // V fragment loads issued here: latency overlaps the softmax below
    bf16x8 bv[2][8];
    #pragma unroll
    for (int kk2 = 0; kk2 < 2; ++kk2)
      #pragma unroll
      for (int jj = 0; jj < 8; ++jj)
        bv[kk2][jj] = *(const bf16x8*)(Vt + (size_t)jj * 1024 + (kk2 * 4 + quad) * 128 + l16 * 8);

    if (it == ntile - 1) {                     // causal mask only on the diagonal tile
      #pragma unroll
      for (int jt = 0; jt < 4; ++jt) {
        int kg = t0 + jt * 16 + quad * 4;
        #pragma unroll
        for (int i = 0; i < 2; ++i) {
          int qg = q0 + i * 16 + l16;
          #pragma unroll
          for (int r = 0; r < 4; ++r)
            if (kg + r > qg) sc[jt][i][r] = -3.0e38f;   // exp -> 0
        }
      }
    }

    // static-max softmax: p = exp(s - 12); per-lane l partials; NO cross-lane ops
    #pragma unroll
    for (int i = 0; i < 2; ++i) {
      float part = 0.f;
      #pragma unroll
      for (int jt = 0; jt < 4; ++jt)
        #pragma unroll
        for (int r = 0; r < 4; ++r) {
          float p = __expf(sc[jt][i][r] - 12.0f);
          sc[jt][i][r] = p; part += p;
        }
      l_i[i] += part;
    }

    // P^T (C-layout) -> private LDS row-major P [q32][k64], packed via v_cvt_pk_bf16_f32
    #pragma unroll
    for (int i = 0; i < 2; ++i)
      #pragma unroll
      for (int jt = 0; jt < 4; ++jt) {
        uint2 uu;
        uu.x = cvt_pk_bf16(sc[jt][i][0], sc[jt][i][1]);
        uu.y = cvt_pk_bf16(sc[jt][i][2], sc[jt][i][3]);
        *(uint2*)(myP + (i * 16 + l16) * 72 + jt * 16 + quad * 4) = uu;
      }

    // O += P V : A from private LDS (in-wave ordering, no barrier), B preloaded above
    #pragma unroll
    for (int kk2 = 0; kk2 < 2; ++kk2) {
      bf16x8 ap[2];
      #pragma unroll
      for (int i = 0; i < 2; ++i)
        ap[i] = *(const bf16x8*)(myP + (i * 16 + l16) * 72 + kk2 * 32 + quad * 8);
      #pragma unroll
      for (int i = 0; i < 2; ++i)
        #pragma unroll
        for (int jj = 0; jj < 8; ++jj)
          o[i][jj] = __builtin_amdgcn_mfma_f32_16x16x32_bf16(ap[i], bv[kk2][jj], o[i][jj], 0, 0, 0);
    }
  }

  // reduce l across quads (valid in all lanes; value for q = i*16 + l16)
  float lsum[2];
  #pragma unroll
  for (int i = 0; i < 2; ++i) {
    float l = l_i[i];
    l += __shfl_xor(l, 16, 64);
    l += __shfl_xor(l, 32, 64);
    lsum[i] = l;
  }

  __syncthreads();                             // all P reads done: safe to reuse smem
  float* oc = (float*)smem + qsel * (32 * 132);           // pair id = qsel
  float* lc = (float*)smem + 2 * (32 * 132) + qsel * 32;
  if (half == 1) {                             // wave-uniform branch
    #pragma unroll
    for (int i = 0; i < 2; ++i) {
      if (quad == 0) lc[i * 16 + l16] = lsum[i];
      #pragma unroll
      for (int jj = 0; jj < 8; ++jj)
        #pragma unroll
        for (int r = 0; r < 4; ++r)
          oc[(i * 16 + quad * 4 + r) * 132 + jj * 16 + l16] = o[i][jj][r];
    }
  }
  __syncthreads();
  if (half == 0) {                             // combine (linear, static max) + store
    #pragma unroll
    for (int i = 0; i < 2; ++i) {
      float l = lsum[i] + lc[i * 16 + l16];
      float linv = 1.0f / l;
      float lr[4];
      #pragma unroll
      for (int r = 0; r < 4; ++r) lr[r] = __shfl(linv, quad * 4 + r, 64);
      #pragma unroll
      for (int r = 0; r < 4; ++r) {
        int tg = q0 + i * 16 + quad * 4 + r;
        unsigned short* yr = yb + (((size_t)(b * T_ + tg)) * H_ + h) * D_;
        #pragma unroll
        for (int jj = 0; jj < 8; ++jj) {
          float vsum = o[i][jj][r] + oc[(i * 16 + quad * 4 + r) * 132 + jj * 16 + l16];
          yr[jj * 16 + l16] = f2b(vsum * lr[r]);
        }
      }
    }
  }
}

extern "C" void kernel_launch(void* const* d_in, const int* in_sizes, int n_in,
                              void* d_out, int out_size, void* d_ws, size_t ws_size,
                              hipStream_t stream) {
  (void)in_sizes; (void)n_in; (void)out_size; (void)ws_size;
  const float* x  = (const float*)d_in[0];
  const float* cs = (const float*)d_in[1];
  const float* sn = (const float*)d_in[2];
  const float* Wq = (const float*)d_in[3];
  const float* Wk = (const float*)d_in[4];
  const float* Wv = (const float*)d_in[5];
  const float* Wo = (const float*)d_in[6];
  float* out = (float*)d_out;
  char* ws = (char*)d_ws;

  // workspace layout (bytes); regions reused across phases. total ~88MB.
  unsigned short* xb   = (unsigned short*)(ws + 0);          // 4096x2048 bf16 (dead after qkv)
  unsigned short* Wqt  = (unsigned short*)(ws + 16777216);   // (dead after qkv)
  unsigned short* Wkt  = (unsigned short*)(ws + 25165824);   // (dead after qkv)
  unsigned short* Wvt  = (unsigned short*)(ws + 27262976);   // (dead after qkv)
  unsigned short* Wot  = (unsigned short*)(ws + 29360128);   // needed until out_gemm
  unsigned short* qraw = (unsigned short*)(ws + 37748736);   // (B,T,H,D) bf16
  unsigned short* kraw = (unsigned short*)(ws + 54525952);   // (dead after ropenorm<4>)
  unsigned short* vraw = (unsigned short*)(ws + 58720256);   // (dead after vfrag)
  unsigned short* qfr  = (unsigned short*)(ws + 62914560);   // Q frag order
  unsigned short* kfr  = (unsigned short*)(ws + 79691776);   // K frag order
  unsigned short* vfr  = (unsigned short*)(ws + 83886080);   // V frag order
  unsigned short* yb   = qraw;                               // attention output (B,T,C) bf16

  cast_bf16_k<<<dim3(8192), dim3(256), 0, stream>>>(x, xb);
  wtrans<<<dim3(64, 64), dim3(32, 8), 0, stream>>>(Wq, Wqt, 2048, 2048);
  wtrans<<<dim3(16, 64), dim3(32, 8), 0, stream>>>(Wk, Wkt, 2048, 512);
  wtrans<<<dim3(16, 64), dim3(32, 8), 0, stream>>>(Wv, Wvt, 2048, 512);
  wtrans<<<dim3(64, 64), dim3(32, 8), 0, stream>>>(Wo, Wot, 2048, 2048);
  qkv_gemm8<<<dim3(192), dim3(512), 0, stream>>>(xb, Wqt, Wkt, Wvt, qraw, kraw, vraw);
  ropenorm<16><<<dim3(16384), dim3(256), 0, stream>>>(qraw, cs, sn, qfr, 0.08838834764831845f);
  ropenorm<4><<<dim3(4096),  dim3(256), 0, stream>>>(kraw, cs, sn, kfr, 1.0f);
  vfrag_k<<<dim3(32, 8), dim3(128, 2), 0, stream>>>(vraw, vfr);
  attn_kernel<<<dim3(8, 128), dim3(256), 0, stream>>>(qfr, kfr, vfr, yb);
  out_gemm<<<dim3(16, 32), dim3(256), 0, stream>>>(yb, Wot, out);
}

// Round 4
// 318.864 us; speedup vs baseline: 1.0145x; 1.0145x over previous
//
#include <hip/hip_runtime.h>

using bf16x8 = __attribute__((ext_vector_type(8))) short;
using f32x4  = __attribute__((ext_vector_type(4))) float;

#define B_  2
#define T_  2048
#define C_  2048
#define H_  16
#define KV_ 4
#define D_  128

__device__ __forceinline__ unsigned short f2b(float f) {
  union { float f; unsigned int u; } v; v.f = f;
  unsigned int r = v.u + 0x7fffu + ((v.u >> 16) & 1u);   // RTNE
  return (unsigned short)(r >> 16);
}
__device__ __forceinline__ float b2f(unsigned short u) {
  union { unsigned int u; float f; } v; v.u = ((unsigned int)u) << 16;
  return v.f;
}
// packed f32x2 -> bf16x2 (RTNE), single VALU op (no gfx950 builtin; T12 recipe)
__device__ __forceinline__ unsigned int cvt_pk_bf16(float lo, float hi) {
  unsigned int r;
  asm("v_cvt_pk_bf16_f32 %0, %1, %2" : "=v"(r) : "v"(lo), "v"(hi));
  return r;
}
// async global->LDS, 16B per lane; LDS dest must be lane-contiguous (wave base + lane*16)
__device__ __forceinline__ void gld_lds16(const void* g, void* l) {
  __builtin_amdgcn_global_load_lds(
      (__attribute__((address_space(1))) void*)g,
      (__attribute__((address_space(3))) void*)l, 16, 0, 0);
}

// ---------------- elementwise cast x -> bf16 ----------------
__global__ void cast_bf16_k(const float* __restrict__ in, unsigned short* __restrict__ out) {
  int i = blockIdx.x * 256 + threadIdx.x;
  float4 f = ((const float4*)in)[i];
  ushort4 u; u.x = f2b(f.x); u.y = f2b(f.y); u.z = f2b(f.z); u.w = f2b(f.w);
  ((ushort4*)out)[i] = u;
}

// ------------- batched transpose-cast: all 4 weights in one launch -------------
// W (2048 x N fp32) -> Wt (N x 2048 bf16). Linear block id decodes matrix + tile.
__global__ void wtrans4(const float* __restrict__ Wq, const float* __restrict__ Wk,
                        const float* __restrict__ Wv, const float* __restrict__ Wo,
                        unsigned short* __restrict__ Wqt, unsigned short* __restrict__ Wkt,
                        unsigned short* __restrict__ Wvt, unsigned short* __restrict__ Wot) {
  __shared__ float s[32][33];
  int id = blockIdx.x;
  const float* W; unsigned short* Wt; int N;
  if (id < 4096)      { W = Wq; Wt = Wqt; N = 2048; }
  else if (id < 5120) { W = Wk; Wt = Wkt; N = 512;  id -= 4096; }
  else if (id < 6144) { W = Wv; Wt = Wvt; N = 512;  id -= 5120; }
  else                { W = Wo; Wt = Wot; N = 2048; id -= 6144; }
  int ntiles = N >> 5;
  int n0 = (id % ntiles) * 32, k0 = (id / ntiles) * 32;
  int tx = threadIdx.x, ty = threadIdx.y;
  #pragma unroll
  for (int yy = 0; yy < 32; yy += 8)
    s[ty + yy][tx] = W[(size_t)(k0 + ty + yy) * N + n0 + tx];
  __syncthreads();
  #pragma unroll
  for (int yy = 0; yy < 32; yy += 8)
    Wt[(size_t)(n0 + ty + yy) * 2048 + k0 + tx] = f2b(s[tx][ty + yy]);
}

// ---------------- m97-style bf16 MFMA GEMM tile: C = A(MxK) * Bt(NxK)^T ----------------
// (kept for out_gemm)
template <bool OUT_BF16>
__device__ __forceinline__ void gemm_tile(
    const unsigned short* __restrict__ A, const unsigned short* __restrict__ Bt,
    void* __restrict__ Cv, int K, int ldc, int m0, int n0b, int n0c,
    unsigned short* sA, unsigned short* sB)
{
  const int tid  = threadIdx.x;
  const int lane = tid & 63, w = tid >> 6;
  const int quad = lane >> 4, l16 = lane & 15;
  const int wm = (w >> 1) * 64, wn = (w & 1) * 64;

  f32x4 acc[4][4] = {};

  const unsigned short* Abase = A  + (size_t)m0  * K;
  const unsigned short* Bbase = Bt + (size_t)n0b * K;

  for (int k0 = 0; k0 < K; k0 += 32) {
    #pragma unroll
    for (int r = 0; r < 2; ++r) {                   // 128x32 bf16 tile = 512 chunks of 16B
      int c = tid + r * 256;
      int row = c >> 2, col = (c & 3) * 8;
      gld_lds16(Abase + (size_t)row * K + k0 + col, sA + c * 8);
      gld_lds16(Bbase + (size_t)row * K + k0 + col, sB + c * 8);
    }
    __syncthreads();                                // drains vmcnt, LDS visible
    bf16x8 af[4], bfr[4];
    #pragma unroll
    for (int i = 0; i < 4; ++i)
      af[i]  = *(const bf16x8*)(sA + (wm + i * 16 + l16) * 32 + quad * 8);
    #pragma unroll
    for (int j = 0; j < 4; ++j)
      bfr[j] = *(const bf16x8*)(sB + (wn + j * 16 + l16) * 32 + quad * 8);
    #pragma unroll
    for (int i = 0; i < 4; ++i)
      #pragma unroll
      for (int j = 0; j < 4; ++j)
        acc[i][j] = __builtin_amdgcn_mfma_f32_16x16x32_bf16(af[i], bfr[j], acc[i][j], 0, 0, 0);
    __syncthreads();                                // all waves done reading before overwrite
  }
  #pragma unroll
  for (int i = 0; i < 4; ++i) {
    #pragma unroll
    for (int r = 0; r < 4; ++r) {
      int row = m0 + wm + i * 16 + quad * 4 + r;    // C/D: row = quad*4+reg, col = lane&15
      #pragma unroll
      for (int j = 0; j < 4; ++j) {
        int col = n0c + wn + j * 16 + l16;
        float v = acc[i][j][r];
        if (OUT_BF16) ((unsigned short*)Cv)[(size_t)row * ldc + col] = f2b(v);
        else          ((float*)Cv)[(size_t)row * ldc + col] = v;
      }
    }
  }
}

__global__ void out_gemm(const unsigned short* __restrict__ yb,
                         const unsigned short* __restrict__ Wot,
                         float* __restrict__ out) {
  __shared__ unsigned short sA[128 * 32], sB[128 * 32];
  gemm_tile<false>(yb, Wot, out, C_, C_, blockIdx.y * 128, blockIdx.x * 128, blockIdx.x * 128,
                   sA, sB);
}

// ------------- qkv GEMM, 256^2 tile, minimal-barrier counted-vmcnt schedule -------------
// v9 post-mortem of v8's 8-phase port (71.4us, MfmaUtil 27.6, = old kernel): pipe math
// says MFMA ~620cyc + LDS ~600-900cyc per K-tile per SIMD => ~25-30us of work; the extra
// ~40us was sync: 8 barriers + 8 lgkm waits per K-tile with only 2 waves/SIMD. This
// version: 2 barriers + 2 counted vmcnt per K-tile. Hazards (buffer parity): stages only
// write buf nxt, reads only touch buf cur, and each wave lgkm(0)-drains its own ds_reads
// before each barrier, so intra-tile barriers are unnecessary.
// Per K-tile t: read ks0 frags | burst-stage ALL 4 half-tiles of t+1 | lgkm(0) |
// 32 MFMA | vmcnt(8)+barrier (K1(t) landed globally) | read ks1 | lgkm(0) | 32 MFMA |
// vmcnt(4)+barrier (K0(t+1) landed). Steady state: enter iter with 4 outstanding
// (K1(t)); +8 burst = 12; vmcnt(8) releases K1(t); vmcnt(4) releases K0(t+1).
// Leads ~600/900 cyc. Last iter uses vmcnt(0). Grid 192 = 16mt x 12nt, XCD-striped.
__global__ __launch_bounds__(512, 2) void qkv_gemm8(
    const unsigned short* __restrict__ xb,
    const unsigned short* __restrict__ Wqt,
    const unsigned short* __restrict__ Wkt,
    const unsigned short* __restrict__ Wvt,
    unsigned short* __restrict__ q, unsigned short* __restrict__ k,
    unsigned short* __restrict__ v) {
  __shared__ unsigned short lds[65536];   // A: [2buf][2kh][256*32] ; B same at +32768

  const int id  = (int)blockIdx.x;        // 0..191; id&7 = XCD (round-robin dispatch)
  const int xcd = id & 7, jj = id >> 3;   // 24 blocks per XCD
  const int mt  = xcd * 2 + jj / 12;
  const int nt  = jj % 12;

  const unsigned short* Bt; unsigned short* Cp; int n0, ldc;
  if (nt < 8)       { Bt = Wqt; Cp = q; n0 = nt * 256;        ldc = 2048; }
  else if (nt < 10) { Bt = Wkt; Cp = k; n0 = (nt - 8) * 256;  ldc = 512;  }
  else              { Bt = Wvt; Cp = v; n0 = (nt - 10) * 256; ldc = 512;  }
  const int m0 = mt * 256;

  const int tid = (int)threadIdx.x;
  const int w = tid >> 6, lane = tid & 63;
  const int quad = lane >> 4, l16 = lane & 15;
  const int wr = w >> 2, wc = w & 3;             // wave tile: rows wr*128, cols wc*64
  const int swz = (l16 & 12) << 1;               // ((row>>2)&3)<<3 with row=...+l16

  const unsigned short* Ab = xb + (size_t)m0 * 2048;
  const unsigned short* Bb = Bt + (size_t)n0 * 2048;

  // staging chunk geometry: 1024 chunks x 16B per half-tile (256 rows x 32 shorts)
  const int c0 = tid, c1 = tid + 512;
  const int r0 = c0 >> 2, r1 = c1 >> 2;
  const int x0 = ((c0 & 3) * 8) ^ (((c0 >> 4) & 3) << 3);   // inverse-swizzled src col
  const int x1 = ((c1 & 3) * 8) ^ (((c1 >> 4) & 3) << 3);

#define STAGE_A(buf, kh, kb) do { \
    unsigned short* d_ = lds + (buf) * 16384 + (kh) * 8192; \
    gld_lds16(Ab + (size_t)r0 * 2048 + (kb) + (kh) * 32 + x0, d_ + c0 * 8); \
    gld_lds16(Ab + (size_t)r1 * 2048 + (kb) + (kh) * 32 + x1, d_ + c1 * 8); \
  } while (0)
#define STAGE_B(buf, kh, kb) do { \
    unsigned short* d_ = lds + 32768 + (buf) * 16384 + (kh) * 8192; \
    gld_lds16(Bb + (size_t)r0 * 2048 + (kb) + (kh) * 32 + x0, d_ + c0 * 8); \
    gld_lds16(Bb + (size_t)r1 * 2048 + (kb) + (kh) * 32 + x1, d_ + c1 * 8); \
  } while (0)

  f32x4 acc[8][4] = {};

  // prologue: stage tile 0 (A-K0, B-K0, A-K1, B-K1); wait K0 halves; barrier
  STAGE_A(0, 0, 0); STAGE_B(0, 0, 0); STAGE_A(0, 1, 0); STAGE_B(0, 1, 0);
  asm volatile("s_waitcnt vmcnt(4)" ::: "memory");
  __builtin_amdgcn_s_barrier();

  const unsigned short* aLd = lds + (wr * 128 + l16) * 32 + (quad * 8 ^ swz);
  const unsigned short* bLd = lds + 32768 + (wc * 64 + l16) * 32 + (quad * 8 ^ swz);

  for (int t = 0; t < 32; ++t) {
    const int cur = t & 1, nxt = cur ^ 1;
    const bool more = (t < 31);
    const int kb = (t + 1) * 64;
    const int off = cur * 16384;
    bf16x8 a[8], bbr[4];

    // ---- K-half 0: read frags, burst-stage tile t+1, 32 MFMA ----
    #pragma unroll
    for (int m = 0; m < 8; ++m) a[m] = *(const bf16x8*)(aLd + off + m * 512);
    #pragma unroll
    for (int n = 0; n < 4; ++n) bbr[n] = *(const bf16x8*)(bLd + off + n * 512);
    if (more) {
      STAGE_A(nxt, 0, kb); STAGE_B(nxt, 0, kb);
      STAGE_A(nxt, 1, kb); STAGE_B(nxt, 1, kb);
    }
    asm volatile("s_waitcnt lgkmcnt(0)" ::: "memory");
    __builtin_amdgcn_sched_barrier(0);
    __builtin_amdgcn_s_setprio(1);
    #pragma unroll
    for (int m = 0; m < 8; ++m)
      #pragma unroll
      for (int n = 0; n < 4; ++n)
        acc[m][n] = __builtin_amdgcn_mfma_f32_16x16x32_bf16(a[m], bbr[n], acc[m][n], 0, 0, 0);
    __builtin_amdgcn_s_setprio(0);
    if (more) asm volatile("s_waitcnt vmcnt(8)" ::: "memory");   // K1(t) landed (own)
    else      asm volatile("s_waitcnt vmcnt(0)" ::: "memory");
    __builtin_amdgcn_s_barrier();                                 // ... and globally

    // ---- K-half 1: read frags, 32 MFMA ----
    #pragma unroll
    for (int m = 0; m < 8; ++m) a[m] = *(const bf16x8*)(aLd + off + 8192 + m * 512);
    #pragma unroll
    for (int n = 0; n < 4; ++n) bbr[n] = *(const bf16x8*)(bLd + off + 8192 + n * 512);
    asm volatile("s_waitcnt lgkmcnt(0)" ::: "memory");
    __builtin_amdgcn_sched_barrier(0);
    __builtin_amdgcn_s_setprio(1);
    #pragma unroll
    for (int m = 0; m < 8; ++m)
      #pragma unroll
      for (int n = 0; n < 4; ++n)
        acc[m][n] = __builtin_amdgcn_mfma_f32_16x16x32_bf16(a[m], bbr[n], acc[m][n], 0, 0, 0);
    __builtin_amdgcn_s_setprio(0);
    if (more) asm volatile("s_waitcnt vmcnt(4)" ::: "memory");   // K0(t+1) landed (own)
    else      asm volatile("s_waitcnt vmcnt(0)" ::: "memory");
    __builtin_amdgcn_s_barrier();                                 // ... and globally
  }
#undef STAGE_A
#undef STAGE_B

  // epilogue: C-layout row = quad*4+reg, col = l16
  #pragma unroll
  for (int m = 0; m < 8; ++m)
    #pragma unroll
    for (int r = 0; r < 4; ++r) {
      int row = m0 + wr * 128 + m * 16 + quad * 4 + r;
      #pragma unroll
      for (int n = 0; n < 4; ++n) {
        int col = n0 + wc * 64 + n * 16 + l16;
        Cp[(size_t)row * ldc + col] = f2b(acc[m][n][r]);
      }
    }
}

// ---------------- RoPE + RMSNorm -> MFMA-fragment-order output ----------------
// v9: vectorized (Common-mistake #2 fix). Lane loads one uint (2 adjacent bf16 at
// d = 2*(lane&31) [+64 for lanes>=32]); RoPE partner pair comes via one shfl_xor(32);
// both outputs computed branchlessly (sign trick) and stored as one packed uint.
// per (b,head): [t16 (128 tiles)][f = d>>3 (16)][t&15 (16)][d&7 (8)]  (tile = 2048 shorts)
template <int NH>
__global__ void ropenorm(const unsigned short* __restrict__ in,
                         const float* __restrict__ cs, const float* __restrict__ sn,
                         unsigned short* __restrict__ out, float oscale) {
  int row  = blockIdx.x * 4 + (threadIdx.x >> 6);
  int lane = threadIdx.x & 63;
  int head = row % NH;
  int t = (row / NH) & (T_ - 1);
  int b = row / (NH * T_);
  const unsigned short* p = in + (size_t)row * D_;
  unsigned int u  = *(const unsigned int*)(p + 2 * lane);     // 2 adjacent bf16
  unsigned int up = (unsigned int)__shfl_xor((int)u, 32, 64); // partner pair (d <-> d+64)
  int dh = (lane & 31) * 2;                                   // d mod 64 (even)
  float2 c2 = ((const float2*)(cs + t * 64))[lane & 31];
  float2 s2 = ((const float2*)(sn + t * 64))[lane & 31];
  float a0 = b2f((unsigned short)(u & 0xffff)),  a1 = b2f((unsigned short)(u >> 16));
  float p0 = b2f((unsigned short)(up & 0xffff)), p1 = b2f((unsigned short)(up >> 16));
  float sgn = (lane < 32) ? 1.0f : -1.0f;   // lane<32: o1 = t1*c + t2*s ; else o2 = t2*c - t1*s
  float oa = a0 * c2.x + sgn * p0 * s2.x;
  float ob = a1 * c2.y + sgn * p1 * s2.y;
  float ss = oa * oa + ob * ob;
  #pragma unroll
  for (int off = 32; off > 0; off >>= 1) ss += __shfl_xor(ss, off, 64);
  float r = rsqrtf(ss * (1.0f / 128.0f) + 1.1920929e-07f) * oscale;
  unsigned int outu = cvt_pk_bf16(oa * r, ob * r);
  size_t base = ((size_t)((b * NH + head) * 128 + (t >> 4))) * 2048 + (size_t)(t & 15) * 8;
  int f = ((lane < 32) ? 0 : 8) + (dh >> 3);
  *(unsigned int*)(out + base + (size_t)f * 128 + (dh & 7)) = outu;
}

// ---------------- V repack: (B,T,KV,D) bf16 -> fragment order for PV B-operand ---------
// per (b,kv): [it (32 tiles of 64 t)][dt = d>>4 (8)][f = (t&63)>>3 (8)][d&15 (16)][t&7 (8)]
__global__ void vfrag_k(const unsigned short* __restrict__ v, unsigned short* __restrict__ vf) {
  int it = blockIdx.x;
  int b = blockIdx.y >> 2, kv = blockIdx.y & 3;
  int d = threadIdx.x, ty = threadIdx.y;
  int t0 = it * 64;
  size_t obase = ((size_t)((b * KV_ + kv) * 32 + it)) * 8192
               + (size_t)(d >> 4) * 1024 + (size_t)(d & 15) * 8;
  #pragma unroll
  for (int tcg = 0; tcg < 4; ++tcg) {
    int tc = ty * 4 + tcg;                   // f chunk 0..7
    unsigned short val[8];
    #pragma unroll
    for (int e = 0; e < 8; ++e)              // coalesced: 128 lanes contiguous in d
      val[e] = v[(((size_t)(b * T_) + t0 + tc * 8 + e) * KV_ + kv) * D_ + d];
    ushort4 u0 = {val[0], val[1], val[2], val[3]};
    ushort4 u1 = {val[4], val[5], val[6], val[7]};
    *(ushort4*)(vf + obase + (size_t)tc * 128)     = u0;
    *(ushort4*)(vf + obase + (size_t)tc * 128 + 4) = u1;
  }
}

// ---------------- flash attention v8: kv-split 2x, static-max softmax ----------------
// Block = 4 waves: w = qsel + 2*half; qsel picks qt in {j,63-j} (uniform block work);
// each wave does kv tiles it = half, half+2, ... and halves merge once via LDS
// (static max M=12 makes the combine LINEAR: o = o_a+o_b, l = l_a+l_b, no rescale).
// grid(8,128): linearId%8 = b*4+kv -> each (b,kv)'s K/V stays on one XCD's L2.
__global__ __launch_bounds__(256, 2) void attn_kernel(
    const unsigned short* __restrict__ qf, const unsigned short* __restrict__ kf,
    const unsigned short* __restrict__ vf, unsigned short* __restrict__ yb) {
  // P: 4 waves x 32x72 shorts = 18432B, dead after loop;
  // reused as combine buf: 2 pairs x (32x132 f32 o + 32 f32 l) = 34048B
  __shared__ __align__(16) char smem[34048];

  const int xp = (int)blockIdx.x;              // 0..7 = b*4+kv  (XCD swizzle)
  const int b = xp >> 2, kv = xp & 3;
  const int yp = (int)blockIdx.y;              // 0..127
  const int j = yp >> 2, hp = yp & 3;
  const int tid = threadIdx.x;
  const int w = tid >> 6, lane = tid & 63;
  const int quad = lane >> 4, l16 = lane & 15;
  const int qsel = w & 1, half = w >> 1;
  const int qt = qsel ? (63 - j) : j;          // paired lengths: block total constant
  const int h = kv * 4 + hp;
  const int q0 = qt * 32;
  const int ntile = (qt >> 1) + 1;
  unsigned short* myP = (unsigned short*)smem + w * (32 * 72);

  const unsigned short* Qf = qf + ((size_t)(b * H_ + h) * 128 + qt * 2) * 2048;
  const unsigned short* Kf = kf + (size_t)(b * KV_ + kv) * 128 * 2048;
  const unsigned short* Vf = vf + (size_t)(b * KV_ + kv) * 32 * 8192;

  // persistent Q fragments (B-operand: n = q row, k = head dim), frag-order (coalesced)
  bf16x8 bq[2][4];
  #pragma unroll
  for (int i = 0; i < 2; ++i)
    #pragma unroll
    for (int kk = 0; kk < 4; ++kk)
      bq[i][kk] = *(const bf16x8*)(Qf + (size_t)i * 2048 + (kk * 4 + quad) * 128 + l16 * 8);

  float l_i[2] = {0.f, 0.f};                   // per-lane partial sum (q = l16 within tile i)
  f32x4 o[2][8] = {};                          // rows q (C-layout), cols d

  for (int it = half; it < ntile; it += 2) {   // this wave's half of the kv tiles
    const int t0 = it * 64;
    const unsigned short* Kt = Kf + (size_t)(it * 4) * 2048;
    const unsigned short* Vt = Vf + (size_t)it * 8192;

    // S^T = K Q^T : 64 k rows (4 tiles) x 32 q cols (2 tiles)
    f32x4 sc[4][2] = {};
    #pragma unroll
    for (int kk = 0; kk < 4; ++kk) {
      bf16x8 ak[4];
      #pragma unroll
      for (int jt = 0; jt < 4; ++jt)
        ak[jt] = *(const bf16x8*)(Kt + (size_t)jt * 2048 + (kk * 4 + quad) * 128 + l16 * 8);
      #pragma unroll
      for (int jt = 0; jt < 4; ++jt)
        #pragma unroll
        for (int i = 0; i < 2; ++i)
          sc[jt][i] = __builtin_amdgcn_mfma_f32_16x16x32_bf16(ak[jt], bq[i][kk], sc[jt][i], 0, 0, 0);
    }

    // V fragment loads issued here: latency overlaps the softmax below
    bf16x8 bv[2][8];
    #pragma unroll
    for (int kk2 = 0; kk2 < 2; ++kk2)
      #pragma unroll
      for (int jj = 0; jj < 8; ++jj)
        bv[kk2][jj] = *(const bf16x8*)(Vt + (size_t)jj * 1024 + (kk2 * 4 + quad) * 128 + l16 * 8);

    if (it == ntile - 1) {                     // causal mask only on the diagonal tile
      #pragma unroll
      for (int jt = 0; jt < 4; ++jt) {
        int kg = t0 + jt * 16 + quad * 4;
        #pragma unroll
        for (int i = 0; i < 2; ++i) {
          int qg = q0 + i * 16 + l16;
          #pragma unroll
          for (int r = 0; r < 4; ++r)
            if (kg + r > qg) sc[jt][i][r] = -3.0e38f;   // exp -> 0
        }
      }
    }

    // static-max softmax: p = exp(s - 12); per-lane l partials; NO cross-lane ops
    #pragma unroll
    for (int i = 0; i < 2; ++i) {
      float part = 0.f;
      #pragma unroll
      for (int jt = 0; jt < 4; ++jt)
        #pragma unroll
        for (int r = 0; r < 4; ++r) {
          float p = __expf(sc[jt][i][r] - 12.0f);
          sc[jt][i][r] = p; part += p;
        }
      l_i[i] += part;
    }

    // P^T (C-layout) -> private LDS row-major P [q32][k64], packed via v_cvt_pk_bf16_f32
    #pragma unroll
    for (int i = 0; i < 2; ++i)
      #pragma unroll
      for (int jt = 0; jt < 4; ++jt) {
        uint2 uu;
        uu.x = cvt_pk_bf16(sc[jt][i][0], sc[jt][i][1]);
        uu.y = cvt_pk_bf16(sc[jt][i][2], sc[jt][i][3]);
        *(uint2*)(myP + (i * 16 + l16) * 72 + jt * 16 + quad * 4) = uu;
      }

    // O += P V : A from private LDS (in-wave ordering, no barrier), B preloaded above
    #pragma unroll
    for (int kk2 = 0; kk2 < 2; ++kk2) {
      bf16x8 ap[2];
      #pragma unroll
      for (int i = 0; i < 2; ++i)
        ap[i] = *(const bf16x8*)(myP + (i * 16 + l16) * 72 + kk2 * 32 + quad * 8);
      #pragma unroll
      for (int i = 0; i < 2; ++i)
        #pragma unroll
        for (int jj = 0; jj < 8; ++jj)
          o[i][jj] = __builtin_amdgcn_mfma_f32_16x16x32_bf16(ap[i], bv[kk2][jj], o[i][jj], 0, 0, 0);
    }
  }

  // reduce l across quads (valid in all lanes; value for q = i*16 + l16)
  float lsum[2];
  #pragma unroll
  for (int i = 0; i < 2; ++i) {
    float l = l_i[i];
    l += __shfl_xor(l, 16, 64);
    l += __shfl_xor(l, 32, 64);
    lsum[i] = l;
  }

  __syncthreads();                             // all P reads done: safe to reuse smem
  float* oc = (float*)smem + qsel * (32 * 132);           // pair id = qsel
  float* lc = (float*)smem + 2 * (32 * 132) + qsel * 32;
  if (half == 1) {                             // wave-uniform branch
    #pragma unroll
    for (int i = 0; i < 2; ++i) {
      if (quad == 0) lc[i * 16 + l16] = lsum[i];
      #pragma unroll
      for (int jj = 0; jj < 8; ++jj)
        #pragma unroll
        for (int r = 0; r < 4; ++r)
          oc[(i * 16 + quad * 4 + r) * 132 + jj * 16 + l16] = o[i][jj][r];
    }
  }
  __syncthreads();
  if (half == 0) {                             // combine (linear, static max) + store
    #pragma unroll
    for (int i = 0; i < 2; ++i) {
      float l = lsum[i] + lc[i * 16 + l16];
      float linv = 1.0f / l;
      float lr[4];
      #pragma unroll
      for (int r = 0; r < 4; ++r) lr[r] = __shfl(linv, quad * 4 + r, 64);
      #pragma unroll
      for (int r = 0; r < 4; ++r) {
        int tg = q0 + i * 16 + quad * 4 + r;
        unsigned short* yr = yb + (((size_t)(b * T_ + tg)) * H_ + h) * D_;
        #pragma unroll
        for (int jj = 0; jj < 8; ++jj) {
          float vsum = o[i][jj][r] + oc[(i * 16 + quad * 4 + r) * 132 + jj * 16 + l16];
          yr[jj * 16 + l16] = f2b(vsum * lr[r]);
        }
      }
    }
  }
}

extern "C" void kernel_launch(void* const* d_in, const int* in_sizes, int n_in,
                              void* d_out, int out_size, void* d_ws, size_t ws_size,
                              hipStream_t stream) {
  (void)in_sizes; (void)n_in; (void)out_size; (void)ws_size;
  const float* x  = (const float*)d_in[0];
  const float* cs = (const float*)d_in[1];
  const float* sn = (const float*)d_in[2];
  const float* Wq = (const float*)d_in[3];
  const float* Wk = (const float*)d_in[4];
  const float* Wv = (const float*)d_in[5];
  const float* Wo = (const float*)d_in[6];
  float* out = (float*)d_out;
  char* ws = (char*)d_ws;

  // workspace layout (bytes); regions reused across phases. total ~88MB.
  unsigned short* xb   = (unsigned short*)(ws + 0);          // 4096x2048 bf16 (dead after qkv)
  unsigned short* Wqt  = (unsigned short*)(ws + 16777216);   // (dead after qkv)
  unsigned short* Wkt  = (unsigned short*)(ws + 25165824);   // (dead after qkv)
  unsigned short* Wvt  = (unsigned short*)(ws + 27262976);   // (dead after qkv)
  unsigned short* Wot  = (unsigned short*)(ws + 29360128);   // needed until out_gemm
  unsigned short* qraw = (unsigned short*)(ws + 37748736);   // (B,T,H,D) bf16
  unsigned short* kraw = (unsigned short*)(ws + 54525952);   // (dead after ropenorm<4>)
  unsigned short* vraw = (unsigned short*)(ws + 58720256);   // (dead after vfrag)
  unsigned short* qfr  = (unsigned short*)(ws + 62914560);   // Q frag order
  unsigned short* kfr  = (unsigned short*)(ws + 79691776);   // K frag order
  unsigned short* vfr  = (unsigned short*)(ws + 83886080);   // V frag order
  unsigned short* yb   = qraw;                               // attention output (B,T,C) bf16

  cast_bf16_k<<<dim3(8192), dim3(256), 0, stream>>>(x, xb);
  wtrans4<<<dim3(10240), dim3(32, 8), 0, stream>>>(Wq, Wk, Wv, Wo, Wqt, Wkt, Wvt, Wot);
  qkv_gemm8<<<dim3(192), dim3(512), 0, stream>>>(xb, Wqt, Wkt, Wvt, qraw, kraw, vraw);
  ropenorm<16><<<dim3(16384), dim3(256), 0, stream>>>(qraw, cs, sn, qfr, 0.08838834764831845f);
  ropenorm<4><<<dim3(4096),  dim3(256), 0, stream>>>(kraw, cs, sn, kfr, 1.0f);
  vfrag_k<<<dim3(32, 8), dim3(128, 2), 0, stream>>>(vraw, vfr);
  attn_kernel<<<dim3(8, 128), dim3(256), 0, stream>>>(qfr, kfr, vfr, yb);
  out_gemm<<<dim3(16, 32), dim3(256), 0, stream>>>(yb, Wot, out);
}

// Round 5
// 306.768 us; speedup vs baseline: 1.0545x; 1.0394x over previous
//
#include <hip/hip_runtime.h>

using bf16x8 = __attribute__((ext_vector_type(8))) short;
using f32x4  = __attribute__((ext_vector_type(4))) float;

#define B_  2
#define T_  2048
#define C_  2048
#define H_  16
#define KV_ 4
#define D_  128

__device__ __forceinline__ unsigned short f2b(float f) {
  union { float f; unsigned int u; } v; v.f = f;
  unsigned int r = v.u + 0x7fffu + ((v.u >> 16) & 1u);   // RTNE
  return (unsigned short)(r >> 16);
}
__device__ __forceinline__ float b2f(unsigned short u) {
  union { unsigned int u; float f; } v; v.u = ((unsigned int)u) << 16;
  return v.f;
}
// packed f32x2 -> bf16x2 (RTNE), single VALU op (no gfx950 builtin; T12 recipe)
__device__ __forceinline__ unsigned int cvt_pk_bf16(float lo, float hi) {
  unsigned int r;
  asm("v_cvt_pk_bf16_f32 %0, %1, %2" : "=v"(r) : "v"(lo), "v"(hi));
  return r;
}
// async global->LDS, 16B per lane; LDS dest must be lane-contiguous (wave base + lane*16)
__device__ __forceinline__ void gld_lds16(const void* g, void* l) {
  __builtin_amdgcn_global_load_lds(
      (__attribute__((address_space(1))) void*)g,
      (__attribute__((address_space(3))) void*)l, 16, 0, 0);
}

// ---------------- elementwise cast x -> bf16 ----------------
__global__ void cast_bf16_k(const float* __restrict__ in, unsigned short* __restrict__ out) {
  int i = blockIdx.x * 256 + threadIdx.x;
  float4 f = ((const float4*)in)[i];
  ushort4 u; u.x = f2b(f.x); u.y = f2b(f.y); u.z = f2b(f.z); u.w = f2b(f.w);
  ((ushort4*)out)[i] = u;
}

// ------------- batched transpose-cast: all 4 weights in one launch -------------
// W (2048 x N fp32) -> Wt (N x 2048 bf16). Wq/Wk/Wv write into ONE contiguous
// Wqkvt (3072 x 2048): rows 0-2047 Q, 2048-2559 K, 2560-3071 V (callers pass offsets).
__global__ void wtrans4(const float* __restrict__ Wq, const float* __restrict__ Wk,
                        const float* __restrict__ Wv, const float* __restrict__ Wo,
                        unsigned short* __restrict__ Wqt, unsigned short* __restrict__ Wkt,
                        unsigned short* __restrict__ Wvt, unsigned short* __restrict__ Wot) {
  __shared__ float s[32][33];
  int id = blockIdx.x;
  const float* W; unsigned short* Wt; int N;
  if (id < 4096)      { W = Wq; Wt = Wqt; N = 2048; }
  else if (id < 5120) { W = Wk; Wt = Wkt; N = 512;  id -= 4096; }
  else if (id < 6144) { W = Wv; Wt = Wvt; N = 512;  id -= 5120; }
  else                { W = Wo; Wt = Wot; N = 2048; id -= 6144; }
  int ntiles = N >> 5;
  int n0 = (id % ntiles) * 32, k0 = (id / ntiles) * 32;
  int tx = threadIdx.x, ty = threadIdx.y;
  #pragma unroll
  for (int yy = 0; yy < 32; yy += 8)
    s[ty + yy][tx] = W[(size_t)(k0 + ty + yy) * N + n0 + tx];
  __syncthreads();
  #pragma unroll
  for (int yy = 0; yy < 32; yy += 8)
    Wt[(size_t)(n0 + ty + yy) * 2048 + k0 + tx] = f2b(s[tx][ty + yy]);
}

// ---------------- m97-style bf16 MFMA GEMM tile (kept for out_gemm) ----------------
template <bool OUT_BF16>
__device__ __forceinline__ void gemm_tile(
    const unsigned short* __restrict__ A, const unsigned short* __restrict__ Bt,
    void* __restrict__ Cv, int K, int ldc, int m0, int n0b, int n0c,
    unsigned short* sA, unsigned short* sB)
{
  const int tid  = threadIdx.x;
  const int lane = tid & 63, w = tid >> 6;
  const int quad = lane >> 4, l16 = lane & 15;
  const int wm = (w >> 1) * 64, wn = (w & 1) * 64;

  f32x4 acc[4][4] = {};

  const unsigned short* Abase = A  + (size_t)m0  * K;
  const unsigned short* Bbase = Bt + (size_t)n0b * K;

  for (int k0 = 0; k0 < K; k0 += 32) {
    #pragma unroll
    for (int r = 0; r < 2; ++r) {                   // 128x32 bf16 tile = 512 chunks of 16B
      int c = tid + r * 256;
      int row = c >> 2, col = (c & 3) * 8;
      gld_lds16(Abase + (size_t)row * K + k0 + col, sA + c * 8);
      gld_lds16(Bbase + (size_t)row * K + k0 + col, sB + c * 8);
    }
    __syncthreads();                                // drains vmcnt, LDS visible
    bf16x8 af[4], bfr[4];
    #pragma unroll
    for (int i = 0; i < 4; ++i)
      af[i]  = *(const bf16x8*)(sA + (wm + i * 16 + l16) * 32 + quad * 8);
    #pragma unroll
    for (int j = 0; j < 4; ++j)
      bfr[j] = *(const bf16x8*)(sB + (wn + j * 16 + l16) * 32 + quad * 8);
    #pragma unroll
    for (int i = 0; i < 4; ++i)
      #pragma unroll
      for (int j = 0; j < 4; ++j)
        acc[i][j] = __builtin_amdgcn_mfma_f32_16x16x32_bf16(af[i], bfr[j], acc[i][j], 0, 0, 0);
    __syncthreads();                                // all waves done reading before overwrite
  }
  #pragma unroll
  for (int i = 0; i < 4; ++i) {
    #pragma unroll
    for (int r = 0; r < 4; ++r) {
      int row = m0 + wm + i * 16 + quad * 4 + r;    // C/D: row = quad*4+reg, col = lane&15
      #pragma unroll
      for (int j = 0; j < 4; ++j) {
        int col = n0c + wn + j * 16 + l16;
        float v = acc[i][j][r];
        if (OUT_BF16) ((unsigned short*)Cv)[(size_t)row * ldc + col] = f2b(v);
        else          ((float*)Cv)[(size_t)row * ldc + col] = v;
      }
    }
  }
}

__global__ void out_gemm(const unsigned short* __restrict__ yb,
                         const unsigned short* __restrict__ Wot,
                         float* __restrict__ out) {
  __shared__ unsigned short sA[128 * 32], sB[128 * 32];
  gemm_tile<false>(yb, Wot, out, C_, C_, blockIdx.y * 128, blockIdx.x * 128, blockIdx.x * 128,
                   sA, sB);
}

// ------------- qkv GEMM v10: fused-N 256x192 tile, compiler-scheduled 2-phase -------------
// v9/v8 post-mortem: BOTH schedule variants landed 71us with identical counters -> the
// common poison was the explicit lgkmcnt(0)+sched_barrier(0) between ds_reads and MFMA:
// it forces a full 24-read drain (~1536 cyc of serialized LDS pipe per CU) before any
// MFMA issues, serializing LDS-time + MFMA-time. For PLAIN ds_reads the compiler emits
// fine-grained lgkmcnt(4/3/1/0) itself (m97 asm); order-pinning defeats it (m141).
// Also: 192-block grid left 64 CUs idle. Fix both:
//  - Q|K|V fused into one 4096x3072 output (single Wqkvt, ldc=3072): BM=256, BN=192
//    -> 16x16 = 256 blocks, exact CU fill, bijective XCD stripe (each XCD: 2 mt rows).
//  - Loop body has NO inline asm: STAGE(t+1) -> plain frag reads + 48 MFMA (compiler
//    interleaves) -> __syncthreads() (its vmcnt(0) is free: stage has a full-iter lead).
//  - 8 waves as 4M x 2N (wave tile 64x96): block LDS-read/K-tile 160KB vs 196KB before.
// LDS 112KB: A [2buf][2kh][256][32sh], B [2buf][2kh][192][32sh]; same verified XOR
// swizzle (16B-chunk ^= (row>>2)&3; inverse applied on the global source).
__global__ __launch_bounds__(512, 2) void qkv_gemm2p(
    const unsigned short* __restrict__ xb,
    const unsigned short* __restrict__ Wt,      // 3072 x 2048 (Q|K|V rows)
    unsigned short* __restrict__ qkv) {         // 4096 x 3072
  __shared__ unsigned short lds[57344];         // A: 32768 sh ; B at +32768: 24576 sh

  const int id  = (int)blockIdx.x;              // 0..255; id&7 = XCD (round-robin)
  const int xcd = id & 7, j = id >> 3;          // 32 blocks per XCD
  const int mt  = xcd * 2 + (j >> 4);           // each XCD owns 2 A-panels (L2-resident)
  const int nt  = j & 15;
  const int m0 = mt * 256, n0 = nt * 192;

  const int tid = (int)threadIdx.x;
  const int w = tid >> 6, lane = tid & 63;
  const int quad = lane >> 4, l16 = lane & 15;
  const int wr = w >> 1, wc = w & 1;            // wave tile: rows wr*64, cols wc*96
  const int swz = (l16 & 12) << 1;              // ((row>>2)&3)<<3 in shorts

  const unsigned short* Ab = xb + (size_t)m0 * 2048;
  const unsigned short* Bb = Wt + (size_t)n0 * 2048;

  // A: 2048 chunks/tile (4/thread): ca = tid+kq*512; kh=ca>>10, row=(ca&1023)>>2, cc=ca&3
  int ar[4], axc[4];
  #pragma unroll
  for (int kq = 0; kq < 4; ++kq) {
    int ca = tid + kq * 512;
    ar[kq]  = (ca & 1023) >> 2;
    axc[kq] = ((ca & 3) * 8) ^ ((((ca & 1023) >> 4) & 3) << 3);   // inverse-swizzled src col
  }
  // B: 1536 chunks/tile (3/thread), kh boundary at 768 is wave-uniform (tid<256)
  const int khb1 = (tid < 256) ? 0 : 1;
  int bidx[3] = { tid, tid + 512 - khb1 * 768, tid + 256 };
  int bkh[3]  = { 0, khb1, 1 };
  int br[3], bxc[3];
  #pragma unroll
  for (int kq = 0; kq < 3; ++kq) {
    br[kq]  = bidx[kq] >> 2;
    bxc[kq] = ((bidx[kq] & 3) * 8) ^ (((bidx[kq] >> 4) & 3) << 3);
  }

#define STAGE(buf, kb) do { \
    unsigned short* da_ = lds + (buf) * 16384; \
    _Pragma("unroll") \
    for (int kq = 0; kq < 4; ++kq) { \
      int ca_ = tid + kq * 512; \
      gld_lds16(Ab + (size_t)ar[kq] * 2048 + (kb) + (ca_ >> 10) * 32 + axc[kq], da_ + ca_ * 8); \
    } \
    unsigned short* db_ = lds + 32768 + (buf) * 12288; \
    _Pragma("unroll") \
    for (int kq = 0; kq < 3; ++kq) \
      gld_lds16(Bb + (size_t)br[kq] * 2048 + (kb) + bkh[kq] * 32 + bxc[kq], \
                db_ + bkh[kq] * 6144 + bidx[kq] * 8); \
  } while (0)

  f32x4 acc[4][6] = {};

  STAGE(0, 0);
  __syncthreads();

  const unsigned short* aB = lds + (wr * 64 + l16) * 32 + (quad * 8 ^ swz);
  const unsigned short* bB = lds + 32768 + (wc * 96 + l16) * 32 + (quad * 8 ^ swz);

  for (int t = 0; t < 32; ++t) {
    const int cur = t & 1;
    if (t < 31) STAGE(cur ^ 1, (t + 1) * 64);   // issue first; reads+MFMA hide it
    #pragma unroll
    for (int kh = 0; kh < 2; ++kh) {
      bf16x8 a[4], b[6];
      #pragma unroll
      for (int m = 0; m < 4; ++m)
        a[m] = *(const bf16x8*)(aB + cur * 16384 + kh * 8192 + m * 512);
      #pragma unroll
      for (int n = 0; n < 6; ++n)
        b[n] = *(const bf16x8*)(bB + cur * 12288 + kh * 6144 + n * 512);
      #pragma unroll
      for (int m = 0; m < 4; ++m)
        #pragma unroll
        for (int n = 0; n < 6; ++n)
          acc[m][n] = __builtin_amdgcn_mfma_f32_16x16x32_bf16(a[m], b[n], acc[m][n], 0, 0, 0);
    }
    __syncthreads();    // vmcnt(0)+lgkm(0)+barrier: stage had full-iter lead -> cheap
  }
#undef STAGE

  // epilogue: C-layout row = quad*4+reg, col = l16
  #pragma unroll
  for (int m = 0; m < 4; ++m)
    #pragma unroll
    for (int r = 0; r < 4; ++r) {
      int row = m0 + wr * 64 + m * 16 + quad * 4 + r;
      #pragma unroll
      for (int n = 0; n < 6; ++n) {
        int col = n0 + wc * 96 + n * 16 + l16;
        qkv[(size_t)row * 3072 + col] = f2b(acc[m][n][r]);
      }
    }
}

// ---------------- RoPE + RMSNorm -> MFMA-fragment-order output ----------------
// Reads from the fused qkv matrix: row ptr = in + (b*T+t)*ld + off + head*128.
// Lane loads one uint (2 adjacent bf16); RoPE partner via shfl_xor(32); packed store.
// per (b,head): [t16 (128 tiles)][f = d>>3 (16)][t&15 (16)][d&7 (8)]  (tile = 2048 shorts)
template <int NH>
__global__ void ropenorm(const unsigned short* __restrict__ in,
                         const float* __restrict__ cs, const float* __restrict__ sn,
                         unsigned short* __restrict__ out, float oscale, int ld, int off) {
  int row  = blockIdx.x * 4 + (threadIdx.x >> 6);
  int lane = threadIdx.x & 63;
  int head = row % NH;
  int t = (row / NH) & (T_ - 1);
  int b = row / (NH * T_);
  const unsigned short* p = in + (size_t)(b * T_ + t) * ld + off + head * D_;
  unsigned int u  = *(const unsigned int*)(p + 2 * lane);     // 2 adjacent bf16
  unsigned int up = (unsigned int)__shfl_xor((int)u, 32, 64); // partner pair (d <-> d+64)
  int dh = (lane & 31) * 2;                                   // d mod 64 (even)
  float2 c2 = ((const float2*)(cs + t * 64))[lane & 31];
  float2 s2 = ((const float2*)(sn + t * 64))[lane & 31];
  float a0 = b2f((unsigned short)(u & 0xffff)),  a1 = b2f((unsigned short)(u >> 16));
  float p0 = b2f((unsigned short)(up & 0xffff)), p1 = b2f((unsigned short)(up >> 16));
  float sgn = (lane < 32) ? 1.0f : -1.0f;   // lane<32: o1 = t1*c + t2*s ; else o2 = t2*c - t1*s
  float oa = a0 * c2.x + sgn * p0 * s2.x;
  float ob = a1 * c2.y + sgn * p1 * s2.y;
  float ss = oa * oa + ob * ob;
  #pragma unroll
  for (int off2 = 32; off2 > 0; off2 >>= 1) ss += __shfl_xor(ss, off2, 64);
  float r = rsqrtf(ss * (1.0f / 128.0f) + 1.1920929e-07f) * oscale;
  unsigned int outu = cvt_pk_bf16(oa * r, ob * r);
  size_t base = ((size_t)((b * NH + head) * 128 + (t >> 4))) * 2048 + (size_t)(t & 15) * 8;
  int f = ((lane < 32) ? 0 : 8) + (dh >> 3);
  *(unsigned int*)(out + base + (size_t)f * 128 + (dh & 7)) = outu;
}

// ---------------- V repack: fused qkv (V at col 2560) -> fragment order ---------
// per (b,kv): [it (32 tiles of 64 t)][dt = d>>4 (8)][f = (t&63)>>3 (8)][d&15 (16)][t&7 (8)]
__global__ void vfrag_k(const unsigned short* __restrict__ qkv, unsigned short* __restrict__ vf) {
  int it = blockIdx.x;
  int b = blockIdx.y >> 2, kv = blockIdx.y & 3;
  int d = threadIdx.x, ty = threadIdx.y;
  int t0 = it * 64;
  size_t obase = ((size_t)((b * KV_ + kv) * 32 + it)) * 8192
               + (size_t)(d >> 4) * 1024 + (size_t)(d & 15) * 8;
  #pragma unroll
  for (int tcg = 0; tcg < 4; ++tcg) {
    int tc = ty * 4 + tcg;                   // f chunk 0..7
    unsigned short val[8];
    #pragma unroll
    for (int e = 0; e < 8; ++e)              // coalesced: 128 lanes contiguous in d
      val[e] = qkv[((size_t)(b * T_) + t0 + tc * 8 + e) * 3072 + 2560 + kv * D_ + d];
    ushort4 u0 = {val[0], val[1], val[2], val[3]};
    ushort4 u1 = {val[4], val[5], val[6], val[7]};
    *(ushort4*)(vf + obase + (size_t)tc * 128)     = u0;
    *(ushort4*)(vf + obase + (size_t)tc * 128 + 4) = u1;
  }
}

// ---------------- flash attention: kv-split 2x, static-max softmax ----------------
// Block = 4 waves: w = qsel + 2*half; qsel picks qt in {j,63-j} (uniform block work);
// each wave does kv tiles it = half, half+2, ... and halves merge once via LDS
// (static max M=12 makes the combine LINEAR: o = o_a+o_b, l = l_a+l_b, no rescale).
// grid(8,128): linearId%8 = b*4+kv -> each (b,kv)'s K/V stays on one XCD's L2.
__global__ __launch_bounds__(256, 2) void attn_kernel(
    const unsigned short* __restrict__ qf, const unsigned short* __restrict__ kf,
    const unsigned short* __restrict__ vf, unsigned short* __restrict__ yb) {
  // P: 4 waves x 32x72 shorts = 18432B, dead after loop;
  // reused as combine buf: 2 pairs x (32x132 f32 o + 32 f32 l) = 34048B
  __shared__ __align__(16) char smem[34048];

  const int xp = (int)blockIdx.x;              // 0..7 = b*4+kv  (XCD swizzle)
  const int b = xp >> 2, kv = xp & 3;
  const int yp = (int)blockIdx.y;              // 0..127
  const int j = yp >> 2, hp = yp & 3;
  const int tid = threadIdx.x;
  const int w = tid >> 6, lane = tid & 63;
  const int quad = lane >> 4, l16 = lane & 15;
  const int qsel = w & 1, half = w >> 1;
  const int qt = qsel ? (63 - j) : j;          // paired lengths: block total constant
  const int h = kv * 4 + hp;
  const int q0 = qt * 32;
  const int ntile = (qt >> 1) + 1;
  unsigned short* myP = (unsigned short*)smem + w * (32 * 72);

  const unsigned short* Qf = qf + ((size_t)(b * H_ + h) * 128 + qt * 2) * 2048;
  const unsigned short* Kf = kf + (size_t)(b * KV_ + kv) * 128 * 2048;
  const unsigned short* Vf = vf + (size_t)(b * KV_ + kv) * 32 * 8192;

  // persistent Q fragments (B-operand: n = q row, k = head dim), frag-order (coalesced)
  bf16x8 bq[2][4];
  #pragma unroll
  for (int i = 0; i < 2; ++i)
    #pragma unroll
    for (int kk = 0; kk < 4; ++kk)
      bq[i][kk] = *(const bf16x8*)(Qf + (size_t)i * 2048 + (kk * 4 + quad) * 128 + l16 * 8);

  float l_i[2] = {0.f, 0.f};                   // per-lane partial sum (q = l16 within tile i)
  f32x4 o[2][8] = {};                          // rows q (C-layout), cols d

  for (int it = half; it < ntile; it += 2) {   // this wave's half of the kv tiles
    const int t0 = it * 64;
    const unsigned short* Kt = Kf + (size_t)(it * 4) * 2048;
    const unsigned short* Vt = Vf + (size_t)it * 8192;

    // S^T = K Q^T : 64 k rows (4 tiles) x 32 q cols (2 tiles)
    f32x4 sc[4][2] = {};
    #pragma unroll
    for (int kk = 0; kk < 4; ++kk) {
      bf16x8 ak[4];
      #pragma unroll
      for (int jt = 0; jt < 4; ++jt)
        ak[jt] = *(const bf16x8*)(Kt + (size_t)jt * 2048 + (kk * 4 + quad) * 128 + l16 * 8);
      #pragma unroll
      for (int jt = 0; jt < 4; ++jt)
        #pragma unroll
        for (int i = 0; i < 2; ++i)
          sc[jt][i] = __builtin_amdgcn_mfma_f32_16x16x32_bf16(ak[jt], bq[i][kk], sc[jt][i], 0, 0, 0);
    }

    // V fragment loads issued here: latency overlaps the softmax below
    bf16x8 bv[2][8];
    #pragma unroll
    for (int kk2 = 0; kk2 < 2; ++kk2)
      #pragma unroll
      for (int jj = 0; jj < 8; ++jj)
        bv[kk2][jj] = *(const bf16x8*)(Vt + (size_t)jj * 1024 + (kk2 * 4 + quad) * 128 + l16 * 8);

    if (it == ntile - 1) {                     // causal mask only on the diagonal tile
      #pragma unroll
      for (int jt = 0; jt < 4; ++jt) {
        int kg = t0 + jt * 16 + quad * 4;
        #pragma unroll
        for (int i = 0; i < 2; ++i) {
          int qg = q0 + i * 16 + l16;
          #pragma unroll
          for (int r = 0; r < 4; ++r)
            if (kg + r > qg) sc[jt][i][r] = -3.0e38f;   // exp -> 0
        }
      }
    }

    // static-max softmax: p = exp(s - 12); per-lane l partials; NO cross-lane ops
    #pragma unroll
    for (int i = 0; i < 2; ++i) {
      float part = 0.f;
      #pragma unroll
      for (int jt = 0; jt < 4; ++jt)
        #pragma unroll
        for (int r = 0; r < 4; ++r) {
          float p = __expf(sc[jt][i][r] - 12.0f);
          sc[jt][i][r] = p; part += p;
        }
      l_i[i] += part;
    }

    // P^T (C-layout) -> private LDS row-major P [q32][k64], packed via v_cvt_pk_bf16_f32
    #pragma unroll
    for (int i = 0; i < 2; ++i)
      #pragma unroll
      for (int jt = 0; jt < 4; ++jt) {
        uint2 uu;
        uu.x = cvt_pk_bf16(sc[jt][i][0], sc[jt][i][1]);
        uu.y = cvt_pk_bf16(sc[jt][i][2], sc[jt][i][3]);
        *(uint2*)(myP + (i * 16 + l16) * 72 + jt * 16 + quad * 4) = uu;
      }

    // O += P V : A from private LDS (in-wave ordering, no barrier), B preloaded above
    #pragma unroll
    for (int kk2 = 0; kk2 < 2; ++kk2) {
      bf16x8 ap[2];
      #pragma unroll
      for (int i = 0; i < 2; ++i)
        ap[i] = *(const bf16x8*)(myP + (i * 16 + l16) * 72 + kk2 * 32 + quad * 8);
      #pragma unroll
      for (int i = 0; i < 2; ++i)
        #pragma unroll
        for (int jj = 0; jj < 8; ++jj)
          o[i][jj] = __builtin_amdgcn_mfma_f32_16x16x32_bf16(ap[i], bv[kk2][jj], o[i][jj], 0, 0, 0);
    }
  }

  // reduce l across quads (valid in all lanes; value for q = i*16 + l16)
  float lsum[2];
  #pragma unroll
  for (int i = 0; i < 2; ++i) {
    float l = l_i[i];
    l += __shfl_xor(l, 16, 64);
    l += __shfl_xor(l, 32, 64);
    lsum[i] = l;
  }

  __syncthreads();                             // all P reads done: safe to reuse smem
  float* oc = (float*)smem + qsel * (32 * 132);           // pair id = qsel
  float* lc = (float*)smem + 2 * (32 * 132) + qsel * 32;
  if (half == 1) {                             // wave-uniform branch
    #pragma unroll
    for (int i = 0; i < 2; ++i) {
      if (quad == 0) lc[i * 16 + l16] = lsum[i];
      #pragma unroll
      for (int jj = 0; jj < 8; ++jj)
        #pragma unroll
        for (int r = 0; r < 4; ++r)
          oc[(i * 16 + quad * 4 + r) * 132 + jj * 16 + l16] = o[i][jj][r];
    }
  }
  __syncthreads();
  if (half == 0) {                             // combine (linear, static max) + store
    #pragma unroll
    for (int i = 0; i < 2; ++i) {
      float l = lsum[i] + lc[i * 16 + l16];
      float linv = 1.0f / l;
      float lr[4];
      #pragma unroll
      for (int r = 0; r < 4; ++r) lr[r] = __shfl(linv, quad * 4 + r, 64);
      #pragma unroll
      for (int r = 0; r < 4; ++r) {
        int tg = q0 + i * 16 + quad * 4 + r;
        unsigned short* yr = yb + (((size_t)(b * T_ + tg)) * H_ + h) * D_;
        #pragma unroll
        for (int jj = 0; jj < 8; ++jj) {
          float vsum = o[i][jj][r] + oc[(i * 16 + quad * 4 + r) * 132 + jj * 16 + l16];
          yr[jj * 16 + l16] = f2b(vsum * lr[r]);
        }
      }
    }
  }
}

extern "C" void kernel_launch(void* const* d_in, const int* in_sizes, int n_in,
                              void* d_out, int out_size, void* d_ws, size_t ws_size,
                              hipStream_t stream) {
  (void)in_sizes; (void)n_in; (void)out_size; (void)ws_size;
  const float* x  = (const float*)d_in[0];
  const float* cs = (const float*)d_in[1];
  const float* sn = (const float*)d_in[2];
  const float* Wq = (const float*)d_in[3];
  const float* Wk = (const float*)d_in[4];
  const float* Wv = (const float*)d_in[5];
  const float* Wo = (const float*)d_in[6];
  float* out = (float*)d_out;
  char* ws = (char*)d_ws;

  // workspace layout (bytes); regions reused across phases. total ~88MB.
  unsigned short* xb     = (unsigned short*)(ws + 0);          // 4096x2048 bf16 (dead after qkv)
  unsigned short* Wqkvt  = (unsigned short*)(ws + 16777216);   // 3072x2048 bf16 (dead after qkv)
  unsigned short* Wot    = (unsigned short*)(ws + 29360128);   // needed until out_gemm
  unsigned short* qkvcat = (unsigned short*)(ws + 37748736);   // 4096x3072 bf16 fused Q|K|V
  unsigned short* qfr    = (unsigned short*)(ws + 62914560);   // Q frag order
  unsigned short* kfr    = (unsigned short*)(ws + 79691776);   // K frag order
  unsigned short* vfr    = (unsigned short*)(ws + 83886080);   // V frag order
  unsigned short* yb     = xb;                                 // attn out (B,T,C) bf16 (xb dead)

  cast_bf16_k<<<dim3(8192), dim3(256), 0, stream>>>(x, xb);
  wtrans4<<<dim3(10240), dim3(32, 8), 0, stream>>>(
      Wq, Wk, Wv, Wo,
      Wqkvt, Wqkvt + (size_t)2048 * 2048, Wqkvt + (size_t)2560 * 2048, Wot);
  qkv_gemm2p<<<dim3(256), dim3(512), 0, stream>>>(xb, Wqkvt, qkvcat);
  ropenorm<16><<<dim3(16384), dim3(256), 0, stream>>>(qkvcat, cs, sn, qfr,
                                                      0.08838834764831845f, 3072, 0);
  ropenorm<4><<<dim3(4096),  dim3(256), 0, stream>>>(qkvcat, cs, sn, kfr, 1.0f, 3072, 2048);
  vfrag_k<<<dim3(32, 8), dim3(128, 2), 0, stream>>>(qkvcat, vfr);
  attn_kernel<<<dim3(8, 128), dim3(256), 0, stream>>>(qfr, kfr, vfr, yb);
  out_gemm<<<dim3(16, 32), dim3(256), 0, stream>>>(yb, Wot, out);
}

// Round 6
// 294.160 us; speedup vs baseline: 1.0997x; 1.0429x over previous
//
#include <hip/hip_runtime.h>

using bf16x8 = __attribute__((ext_vector_type(8))) short;
using f32x4  = __attribute__((ext_vector_type(4))) float;

#define B_  2
#define T_  2048
#define C_  2048
#define H_  16
#define KV_ 4
#define D_  128

__device__ __forceinline__ unsigned short f2b(float f) {
  union { float f; unsigned int u; } v; v.f = f;
  unsigned int r = v.u + 0x7fffu + ((v.u >> 16) & 1u);   // RTNE
  return (unsigned short)(r >> 16);
}
__device__ __forceinline__ float b2f(unsigned short u) {
  union { unsigned int u; float f; } v; v.u = ((unsigned int)u) << 16;
  return v.f;
}
// packed f32x2 -> bf16x2 (RTNE), single VALU op (no gfx950 builtin; T12 recipe)
__device__ __forceinline__ unsigned int cvt_pk_bf16(float lo, float hi) {
  unsigned int r;
  asm("v_cvt_pk_bf16_f32 %0, %1, %2" : "=v"(r) : "v"(lo), "v"(hi));
  return r;
}
// async global->LDS, 16B per lane; LDS dest must be lane-contiguous (wave base + lane*16)
__device__ __forceinline__ void gld_lds16(const void* g, void* l) {
  __builtin_amdgcn_global_load_lds(
      (__attribute__((address_space(1))) void*)g,
      (__attribute__((address_space(3))) void*)l, 16, 0, 0);
}

// ---------------- elementwise cast x -> bf16 ----------------
__global__ void cast_bf16_k(const float* __restrict__ in, unsigned short* __restrict__ out) {
  int i = blockIdx.x * 256 + threadIdx.x;
  float4 f = ((const float4*)in)[i];
  ushort4 u; u.x = f2b(f.x); u.y = f2b(f.y); u.z = f2b(f.z); u.w = f2b(f.w);
  ((ushort4*)out)[i] = u;
}

// ------------- batched transpose-cast: all 4 weights in one launch -------------
// W (2048 x N fp32) -> Wt (N x 2048 bf16). Wq/Wk/Wv write into ONE contiguous
// Wqkvt (3072 x 2048): rows 0-2047 Q, 2048-2559 K, 2560-3071 V (callers pass offsets).
__global__ void wtrans4(const float* __restrict__ Wq, const float* __restrict__ Wk,
                        const float* __restrict__ Wv, const float* __restrict__ Wo,
                        unsigned short* __restrict__ Wqt, unsigned short* __restrict__ Wkt,
                        unsigned short* __restrict__ Wvt, unsigned short* __restrict__ Wot) {
  __shared__ float s[32][33];
  int id = blockIdx.x;
  const float* W; unsigned short* Wt; int N;
  if (id < 4096)      { W = Wq; Wt = Wqt; N = 2048; }
  else if (id < 5120) { W = Wk; Wt = Wkt; N = 512;  id -= 4096; }
  else if (id < 6144) { W = Wv; Wt = Wvt; N = 512;  id -= 5120; }
  else                { W = Wo; Wt = Wot; N = 2048; id -= 6144; }
  int ntiles = N >> 5;
  int n0 = (id % ntiles) * 32, k0 = (id / ntiles) * 32;
  int tx = threadIdx.x, ty = threadIdx.y;
  #pragma unroll
  for (int yy = 0; yy < 32; yy += 8)
    s[ty + yy][tx] = W[(size_t)(k0 + ty + yy) * N + n0 + tx];
  __syncthreads();
  #pragma unroll
  for (int yy = 0; yy < 32; yy += 8)
    Wt[(size_t)(n0 + ty + yy) * 2048 + k0 + tx] = f2b(s[tx][ty + yy]);
}

// ---------------- m97-style bf16 MFMA GEMM tile (kept for out_gemm) ----------------
template <bool OUT_BF16>
__device__ __forceinline__ void gemm_tile(
    const unsigned short* __restrict__ A, const unsigned short* __restrict__ Bt,
    void* __restrict__ Cv, int K, int ldc, int m0, int n0b, int n0c,
    unsigned short* sA, unsigned short* sB)
{
  const int tid  = threadIdx.x;
  const int lane = tid & 63, w = tid >> 6;
  const int quad = lane >> 4, l16 = lane & 15;
  const int wm = (w >> 1) * 64, wn = (w & 1) * 64;

  f32x4 acc[4][4] = {};

  const unsigned short* Abase = A  + (size_t)m0  * K;
  const unsigned short* Bbase = Bt + (size_t)n0b * K;

  for (int k0 = 0; k0 < K; k0 += 32) {
    #pragma unroll
    for (int r = 0; r < 2; ++r) {                   // 128x32 bf16 tile = 512 chunks of 16B
      int c = tid + r * 256;
      int row = c >> 2, col = (c & 3) * 8;
      gld_lds16(Abase + (size_t)row * K + k0 + col, sA + c * 8);
      gld_lds16(Bbase + (size_t)row * K + k0 + col, sB + c * 8);
    }
    __syncthreads();                                // drains vmcnt, LDS visible
    bf16x8 af[4], bfr[4];
    #pragma unroll
    for (int i = 0; i < 4; ++i)
      af[i]  = *(const bf16x8*)(sA + (wm + i * 16 + l16) * 32 + quad * 8);
    #pragma unroll
    for (int j = 0; j < 4; ++j)
      bfr[j] = *(const bf16x8*)(sB + (wn + j * 16 + l16) * 32 + quad * 8);
    #pragma unroll
    for (int i = 0; i < 4; ++i)
      #pragma unroll
      for (int j = 0; j < 4; ++j)
        acc[i][j] = __builtin_amdgcn_mfma_f32_16x16x32_bf16(af[i], bfr[j], acc[i][j], 0, 0, 0);
    __syncthreads();                                // all waves done reading before overwrite
  }
  #pragma unroll
  for (int i = 0; i < 4; ++i) {
    #pragma unroll
    for (int r = 0; r < 4; ++r) {
      int row = m0 + wm + i * 16 + quad * 4 + r;    // C/D: row = quad*4+reg, col = lane&15
      #pragma unroll
      for (int j = 0; j < 4; ++j) {
        int col = n0c + wn + j * 16 + l16;
        float v = acc[i][j][r];
        if (OUT_BF16) ((unsigned short*)Cv)[(size_t)row * ldc + col] = f2b(v);
        else          ((float*)Cv)[(size_t)row * ldc + col] = v;
      }
    }
  }
}

__global__ void out_gemm(const unsigned short* __restrict__ yb,
                         const unsigned short* __restrict__ Wot,
                         float* __restrict__ out) {
  __shared__ unsigned short sA[128 * 32], sB[128 * 32];
  gemm_tile<false>(yb, Wot, out, C_, C_, blockIdx.y * 128, blockIdx.x * 128, blockIdx.x * 128,
                   sA, sB);
}

// ------------- qkv GEMM: fused-N 256x192 tile, compiler-scheduled 2-phase -------------
// (v10, verified: <66us. Plain ds_reads, compiler-scheduled; 256-block exact CU fill.)
__global__ __launch_bounds__(512, 2) void qkv_gemm2p(
    const unsigned short* __restrict__ xb,
    const unsigned short* __restrict__ Wt,      // 3072 x 2048 (Q|K|V rows)
    unsigned short* __restrict__ qkv) {         // 4096 x 3072
  __shared__ unsigned short lds[57344];         // A: 32768 sh ; B at +32768: 24576 sh

  const int id  = (int)blockIdx.x;              // 0..255; id&7 = XCD (round-robin)
  const int xcd = id & 7, j = id >> 3;          // 32 blocks per XCD
  const int mt  = xcd * 2 + (j >> 4);           // each XCD owns 2 A-panels (L2-resident)
  const int nt  = j & 15;
  const int m0 = mt * 256, n0 = nt * 192;

  const int tid = (int)threadIdx.x;
  const int w = tid >> 6, lane = tid & 63;
  const int quad = lane >> 4, l16 = lane & 15;
  const int wr = w >> 1, wc = w & 1;            // wave tile: rows wr*64, cols wc*96
  const int swz = (l16 & 12) << 1;              // ((row>>2)&3)<<3 in shorts

  const unsigned short* Ab = xb + (size_t)m0 * 2048;
  const unsigned short* Bb = Wt + (size_t)n0 * 2048;

  // A: 2048 chunks/tile (4/thread): ca = tid+kq*512; kh=ca>>10, row=(ca&1023)>>2, cc=ca&3
  int ar[4], axc[4];
  #pragma unroll
  for (int kq = 0; kq < 4; ++kq) {
    int ca = tid + kq * 512;
    ar[kq]  = (ca & 1023) >> 2;
    axc[kq] = ((ca & 3) * 8) ^ ((((ca & 1023) >> 4) & 3) << 3);   // inverse-swizzled src col
  }
  // B: 1536 chunks/tile (3/thread), kh boundary at 768 is wave-uniform (tid<256)
  const int khb1 = (tid < 256) ? 0 : 1;
  int bidx[3] = { tid, tid + 512 - khb1 * 768, tid + 256 };
  int bkh[3]  = { 0, khb1, 1 };
  int br[3], bxc[3];
  #pragma unroll
  for (int kq = 0; kq < 3; ++kq) {
    br[kq]  = bidx[kq] >> 2;
    bxc[kq] = ((bidx[kq] & 3) * 8) ^ (((bidx[kq] >> 4) & 3) << 3);
  }

#define STAGE(buf, kb) do { \
    unsigned short* da_ = lds + (buf) * 16384; \
    _Pragma("unroll") \
    for (int kq = 0; kq < 4; ++kq) { \
      int ca_ = tid + kq * 512; \
      gld_lds16(Ab + (size_t)ar[kq] * 2048 + (kb) + (ca_ >> 10) * 32 + axc[kq], da_ + ca_ * 8); \
    } \
    unsigned short* db_ = lds + 32768 + (buf) * 12288; \
    _Pragma("unroll") \
    for (int kq = 0; kq < 3; ++kq) \
      gld_lds16(Bb + (size_t)br[kq] * 2048 + (kb) + bkh[kq] * 32 + bxc[kq], \
                db_ + bkh[kq] * 6144 + bidx[kq] * 8); \
  } while (0)

  f32x4 acc[4][6] = {};

  STAGE(0, 0);
  __syncthreads();

  const unsigned short* aB = lds + (wr * 64 + l16) * 32 + (quad * 8 ^ swz);
  const unsigned short* bB = lds + 32768 + (wc * 96 + l16) * 32 + (quad * 8 ^ swz);

  for (int t = 0; t < 32; ++t) {
    const int cur = t & 1;
    if (t < 31) STAGE(cur ^ 1, (t + 1) * 64);   // issue first; reads+MFMA hide it
    #pragma unroll
    for (int kh = 0; kh < 2; ++kh) {
      bf16x8 a[4], b[6];
      #pragma unroll
      for (int m = 0; m < 4; ++m)
        a[m] = *(const bf16x8*)(aB + cur * 16384 + kh * 8192 + m * 512);
      #pragma unroll
      for (int n = 0; n < 6; ++n)
        b[n] = *(const bf16x8*)(bB + cur * 12288 + kh * 6144 + n * 512);
      #pragma unroll
      for (int m = 0; m < 4; ++m)
        #pragma unroll
        for (int n = 0; n < 6; ++n)
          acc[m][n] = __builtin_amdgcn_mfma_f32_16x16x32_bf16(a[m], b[n], acc[m][n], 0, 0, 0);
    }
    __syncthreads();    // vmcnt(0)+lgkm(0)+barrier: stage had full-iter lead -> cheap
  }
#undef STAGE

  // epilogue: C-layout row = quad*4+reg, col = l16
  #pragma unroll
  for (int m = 0; m < 4; ++m)
    #pragma unroll
    for (int r = 0; r < 4; ++r) {
      int row = m0 + wr * 64 + m * 16 + quad * 4 + r;
      #pragma unroll
      for (int n = 0; n < 6; ++n) {
        int col = n0 + wc * 96 + n * 16 + l16;
        qkv[(size_t)row * 3072 + col] = f2b(acc[m][n][r]);
      }
    }
}

// ---------------- RoPE + RMSNorm -> MFMA-fragment-order output ----------------
// Reads from the fused qkv matrix: row ptr = in + (b*T+t)*ld + off + head*128.
// Lane loads one uint (2 adjacent bf16); RoPE partner via shfl_xor(32); packed store.
// per (b,head): [t16 (128 tiles)][f = d>>3 (16)][t&15 (16)][d&7 (8)]  (tile = 2048 shorts)
template <int NH>
__global__ void ropenorm(const unsigned short* __restrict__ in,
                         const float* __restrict__ cs, const float* __restrict__ sn,
                         unsigned short* __restrict__ out, float oscale, int ld, int off) {
  int row  = blockIdx.x * 4 + (threadIdx.x >> 6);
  int lane = threadIdx.x & 63;
  int head = row % NH;
  int t = (row / NH) & (T_ - 1);
  int b = row / (NH * T_);
  const unsigned short* p = in + (size_t)(b * T_ + t) * ld + off + head * D_;
  unsigned int u  = *(const unsigned int*)(p + 2 * lane);     // 2 adjacent bf16
  unsigned int up = (unsigned int)__shfl_xor((int)u, 32, 64); // partner pair (d <-> d+64)
  int dh = (lane & 31) * 2;                                   // d mod 64 (even)
  float2 c2 = ((const float2*)(cs + t * 64))[lane & 31];
  float2 s2 = ((const float2*)(sn + t * 64))[lane & 31];
  float a0 = b2f((unsigned short)(u & 0xffff)),  a1 = b2f((unsigned short)(u >> 16));
  float p0 = b2f((unsigned short)(up & 0xffff)), p1 = b2f((unsigned short)(up >> 16));
  float sgn = (lane < 32) ? 1.0f : -1.0f;   // lane<32: o1 = t1*c + t2*s ; else o2 = t2*c - t1*s
  float oa = a0 * c2.x + sgn * p0 * s2.x;
  float ob = a1 * c2.y + sgn * p1 * s2.y;
  float ss = oa * oa + ob * ob;
  #pragma unroll
  for (int off2 = 32; off2 > 0; off2 >>= 1) ss += __shfl_xor(ss, off2, 64);
  float r = rsqrtf(ss * (1.0f / 128.0f) + 1.1920929e-07f) * oscale;
  unsigned int outu = cvt_pk_bf16(oa * r, ob * r);
  size_t base = ((size_t)((b * NH + head) * 128 + (t >> 4))) * 2048 + (size_t)(t & 15) * 8;
  int f = ((lane < 32) ? 0 : 8) + (dh >> 3);
  *(unsigned int*)(out + base + (size_t)f * 128 + (dh & 7)) = outu;
}

// ---------------- V repack: fused qkv (V at col 2560) -> fragment order ---------
// per (b,kv): [it (32 tiles of 64 t)][dt = d>>4 (8)][f = (t&63)>>3 (8)][d&15 (16)][t&7 (8)]
__global__ void vfrag_k(const unsigned short* __restrict__ qkv, unsigned short* __restrict__ vf) {
  int it = blockIdx.x;
  int b = blockIdx.y >> 2, kv = blockIdx.y & 3;
  int d = threadIdx.x, ty = threadIdx.y;
  int t0 = it * 64;
  size_t obase = ((size_t)((b * KV_ + kv) * 32 + it)) * 8192
               + (size_t)(d >> 4) * 1024 + (size_t)(d & 15) * 8;
  #pragma unroll
  for (int tcg = 0; tcg < 4; ++tcg) {
    int tc = ty * 4 + tcg;                   // f chunk 0..7
    unsigned short val[8];
    #pragma unroll
    for (int e = 0; e < 8; ++e)              // coalesced: 128 lanes contiguous in d
      val[e] = qkv[((size_t)(b * T_) + t0 + tc * 8 + e) * 3072 + 2560 + kv * D_ + d];
    ushort4 u0 = {val[0], val[1], val[2], val[3]};
    ushort4 u1 = {val[4], val[5], val[6], val[7]};
    *(ushort4*)(vf + obase + (size_t)tc * 128)     = u0;
    *(ushort4*)(vf + obase + (size_t)tc * 128 + 4) = u1;
  }
}

// ------------ flash attention v11: head-shared LDS K/V staging, uniform blocks ------------
// v10 evidence: attn 66us; MfmaUtil 20.6 (MFMA work ~15us), L2 traffic 33792 tiles x 32KB
// = 1.08GB -> >=31us L2 floor; plus intra-block wave imbalance ({j,63-j} waves gate each
// other). Fix: share K/V across the kv-group's 4 heads via LDS (traffic /4 = 278MB) and
// make every wave's work identical.
//   Block = 8 waves = 4 heads x 2 kv-halves, 512 thr. Processes qt = j then qt = 63-j
//   sequentially -> every block 17 rounds, grid (8,32) = 256 blocks = 1/CU all-resident.
//   Per round r: stage V(2r),V(2r+1) (single-buf) + K(2r+2),K(2r+3) (double-buf) via
//   global_load_lds; counted vmcnt (own queue per wave: 4 K-insts + 4 V-insts/round):
//     [STAGE_V; STAGE_K(nxt); vmcnt(8); bar] K landed -> QK+softmax+P
//     [vmcnt(4); bar] V landed -> PV ; [bar] protects vls for next round. Never drains
//   mid-loop (8->4->... ; last round 4->0). Q-loads/stores only make waits conservative.
//   K/V LDS reads 4-way quad-conflict -> XOR-swizzle chunk^(quad<<1) (= shorts ^ quad<<4),
//   applied on stage SOURCE + read (both-sides rule, same scheme as qkv_gemm2p).
//   LDS: K 64KB | V 32KB | P 8x4.6KB = 132KB; combine scratch reuses dead K/V region.
//   Static max M=12 (|s|<=11.4 bound) -> halves combine LINEARLY (o,l add; no rescale).
__global__ __launch_bounds__(512, 2) void attn_kernel(
    const unsigned short* __restrict__ qf, const unsigned short* __restrict__ kf,
    const unsigned short* __restrict__ vf, unsigned short* __restrict__ yb) {
  __shared__ __align__(16) char smem[135168];
  unsigned short* kls = (unsigned short*)smem;            // [2 buf][2 slot][8192 sh]
  unsigned short* vls = (unsigned short*)(smem + 65536);  // [2 slot][8192 sh]
  unsigned short* Pls = (unsigned short*)(smem + 98304);  // 8 waves x 32x72 sh

  const int xp = (int)blockIdx.x, b = xp >> 2, kv = xp & 3;   // XCD swizzle: id%8 = xp
  const int jy = (int)blockIdx.y;                             // 0..31
  const int tid = (int)threadIdx.x;
  const int w = tid >> 6, lane = tid & 63;
  const int quad = lane >> 4, l16 = lane & 15;
  const int hh = w & 3, half = w >> 2;
  const int h = kv * 4 + hh;
  unsigned short* myP = Pls + w * (32 * 72);

  const unsigned short* Kf = kf + (size_t)(b * KV_ + kv) * 128 * 2048;
  const unsigned short* Vf = vf + (size_t)(b * KV_ + kv) * 32 * 8192;

  const int swl = quad << 4;                 // swizzle key (shorts): chunk ^ (quad<<1)
  const int cs0 = (tid * 8) ^ swl;           // staging source offsets within a 16KB tile
  const int cs1 = ((tid + 512) * 8) ^ swl;
  const int cd0 = tid * 8, cd1 = tid * 8 + 4096;   // linear LDS dest (lane-contiguous)

#define STAGE_K(buf, it0) do { \
    const unsigned short* s_ = Kf + (size_t)(it0) * 8192; \
    unsigned short* d_ = kls + (buf) * 16384; \
    gld_lds16(s_ + cs0, d_ + cd0);               gld_lds16(s_ + cs1, d_ + cd1); \
    gld_lds16(s_ + 8192 + cs0, d_ + 8192 + cd0); gld_lds16(s_ + 8192 + cs1, d_ + 8192 + cd1); \
  } while (0)
#define STAGE_V(it0) do { \
    const unsigned short* s_ = Vf + (size_t)(it0) * 8192; \
    gld_lds16(s_ + cs0, vls + cd0);               gld_lds16(s_ + cs1, vls + cd1); \
    gld_lds16(s_ + 8192 + cs0, vls + 8192 + cd0); gld_lds16(s_ + 8192 + cs1, vls + 8192 + cd1); \
  } while (0)

  for (int ph = 0; ph < 2; ++ph) {
    const int qt = ph ? (63 - jy) : jy;
    const int q0 = qt * 32;
    const int ntile = (qt >> 1) + 1;
    const int R = (ntile + 1) >> 1;

    // persistent Q fragments (B-operand: n = q row, k = head dim)
    const unsigned short* Qf = qf + ((size_t)(b * H_ + h) * 128 + qt * 2) * 2048;
    bf16x8 bq[2][4];
    #pragma unroll
    for (int i = 0; i < 2; ++i)
      #pragma unroll
      for (int kk = 0; kk < 4; ++kk)
        bq[i][kk] = *(const bf16x8*)(Qf + (size_t)i * 2048 + (kk * 4 + quad) * 128 + l16 * 8);

    float l_i[2] = {0.f, 0.f};
    f32x4 o[2][8] = {};

    STAGE_K(0, 0);                           // prologue: K tiles 0,1 -> buf 0

    for (int r = 0; r < R; ++r) {
      const int cur = r & 1;
      const bool more = (r + 1 < R);
      STAGE_V(2 * r);
      if (more) STAGE_K(cur ^ 1, 2 * r + 2);
      if (more) asm volatile("s_waitcnt vmcnt(8)" ::: "memory");  // K(2r,2r+1) landed (own)
      else      asm volatile("s_waitcnt vmcnt(4)" ::: "memory");
      __builtin_amdgcn_s_barrier();                               // ...and globally

      const int it = 2 * r + half;
      const bool active = it < ntile;        // wave-uniform
      f32x4 sc[4][2] = {};
      if (active) {
        const unsigned short* kb = kls + cur * 16384 + half * 8192;
        #pragma unroll
        for (int kk = 0; kk < 4; ++kk) {
          bf16x8 ak[4];
          #pragma unroll
          for (int jt = 0; jt < 4; ++jt)
            ak[jt] = *(const bf16x8*)(kb + ((jt * 2048 + (kk * 4 + quad) * 128 + l16 * 8) ^ swl));
          #pragma unroll
          for (int jt = 0; jt < 4; ++jt)
            #pragma unroll
            for (int i = 0; i < 2; ++i)
              sc[jt][i] = __builtin_amdgcn_mfma_f32_16x16x32_bf16(ak[jt], bq[i][kk], sc[jt][i], 0, 0, 0);
        }
        if (it == ntile - 1) {               // causal mask on the diagonal tile
          #pragma unroll
          for (int jt = 0; jt < 4; ++jt) {
            int kg = it * 64 + jt * 16 + quad * 4;
            #pragma unroll
            for (int i = 0; i < 2; ++i) {
              int qg = q0 + i * 16 + l16;
              #pragma unroll
              for (int rr = 0; rr < 4; ++rr)
                if (kg + rr > qg) sc[jt][i][rr] = -3.0e38f;
            }
          }
        }
        // static-max softmax: p = exp(s - 12); per-lane l partials
        #pragma unroll
        for (int i = 0; i < 2; ++i) {
          float part = 0.f;
          #pragma unroll
          for (int jt = 0; jt < 4; ++jt)
            #pragma unroll
            for (int rr = 0; rr < 4; ++rr) {
              float p = __expf(sc[jt][i][rr] - 12.0f);
              sc[jt][i][rr] = p; part += p;
            }
          l_i[i] += part;
        }
        // P^T (C-layout) -> private LDS row-major P [q32][k64]
        #pragma unroll
        for (int i = 0; i < 2; ++i)
          #pragma unroll
          for (int jt = 0; jt < 4; ++jt) {
            uint2 uu;
            uu.x = cvt_pk_bf16(sc[jt][i][0], sc[jt][i][1]);
            uu.y = cvt_pk_bf16(sc[jt][i][2], sc[jt][i][3]);
            *(uint2*)(myP + (i * 16 + l16) * 72 + jt * 16 + quad * 4) = uu;
          }
      }

      if (more) asm volatile("s_waitcnt vmcnt(4)" ::: "memory");  // V(2r,2r+1) landed
      else      asm volatile("s_waitcnt vmcnt(0)" ::: "memory");
      __builtin_amdgcn_s_barrier();

      if (active) {
        const unsigned short* vb = vls + half * 8192;
        #pragma unroll
        for (int kk2 = 0; kk2 < 2; ++kk2) {
          bf16x8 ap[2], bv2[8];
          #pragma unroll
          for (int i = 0; i < 2; ++i)
            ap[i] = *(const bf16x8*)(myP + (i * 16 + l16) * 72 + kk2 * 32 + quad * 8);
          #pragma unroll
          for (int jj = 0; jj < 8; ++jj)
            bv2[jj] = *(const bf16x8*)(vb + ((jj * 1024 + (kk2 * 4 + quad) * 128 + l16 * 8) ^ swl));
          #pragma unroll
          for (int i = 0; i < 2; ++i)
            #pragma unroll
            for (int jj = 0; jj < 8; ++jj)
              o[i][jj] = __builtin_amdgcn_mfma_f32_16x16x32_bf16(ap[i], bv2[jj], o[i][jj], 0, 0, 0);
        }
      }
      __builtin_amdgcn_s_barrier();          // all PV reads done before next STAGE_V
    }

    // reduce l across quads
    float lsum[2];
    #pragma unroll
    for (int i = 0; i < 2; ++i) {
      float l = l_i[i];
      l += __shfl_xor(l, 16, 64);
      l += __shfl_xor(l, 32, 64);
      lsum[i] = l;
    }

    __syncthreads();                         // rounds done; kls/vls dead -> combine scratch
    float* oc = (float*)smem + hh * 4256;    // per head: 32x132 o + 32 l floats (68KB < 96KB)
    float* lc = oc + 32 * 132;
    if (half == 1) {
      #pragma unroll
      for (int i = 0; i < 2; ++i) {
        if (quad == 0) lc[i * 16 + l16] = lsum[i];
        #pragma unroll
        for (int jj = 0; jj < 8; ++jj)
          #pragma unroll
          for (int rr = 0; rr < 4; ++rr)
            oc[(i * 16 + quad * 4 + rr) * 132 + jj * 16 + l16] = o[i][jj][rr];
      }
    }
    __syncthreads();
    if (half == 0) {                         // linear combine (static max) + store
      #pragma unroll
      for (int i = 0; i < 2; ++i) {
        float l = lsum[i] + lc[i * 16 + l16];
        float linv = 1.0f / l;
        float lr[4];
        #pragma unroll
        for (int rr = 0; rr < 4; ++rr) lr[rr] = __shfl(linv, quad * 4 + rr, 64);
        #pragma unroll
        for (int rr = 0; rr < 4; ++rr) {
          int tg = q0 + i * 16 + quad * 4 + rr;
          unsigned short* yr = yb + (((size_t)(b * T_ + tg)) * H_ + h) * D_;
          #pragma unroll
          for (int jj = 0; jj < 8; ++jj) {
            float vsum = o[i][jj][rr] + oc[(i * 16 + quad * 4 + rr) * 132 + jj * 16 + l16];
            yr[jj * 16 + l16] = f2b(vsum * lr[rr]);
          }
        }
      }
    }
    __syncthreads();                         // scratch reads done before next phase stages
  }
#undef STAGE_K
#undef STAGE_V
}

extern "C" void kernel_launch(void* const* d_in, const int* in_sizes, int n_in,
                              void* d_out, int out_size, void* d_ws, size_t ws_size,
                              hipStream_t stream) {
  (void)in_sizes; (void)n_in; (void)out_size; (void)ws_size;
  const float* x  = (const float*)d_in[0];
  const float* cs = (const float*)d_in[1];
  const float* sn = (const float*)d_in[2];
  const float* Wq = (const float*)d_in[3];
  const float* Wk = (const float*)d_in[4];
  const float* Wv = (const float*)d_in[5];
  const float* Wo = (const float*)d_in[6];
  float* out = (float*)d_out;
  char* ws = (char*)d_ws;

  // workspace layout (bytes); regions reused across phases. total ~88MB.
  unsigned short* xb     = (unsigned short*)(ws + 0);          // 4096x2048 bf16 (dead after qkv)
  unsigned short* Wqkvt  = (unsigned short*)(ws + 16777216);   // 3072x2048 bf16 (dead after qkv)
  unsigned short* Wot    = (unsigned short*)(ws + 29360128);   // needed until out_gemm
  unsigned short* qkvcat = (unsigned short*)(ws + 37748736);   // 4096x3072 bf16 fused Q|K|V
  unsigned short* qfr    = (unsigned short*)(ws + 62914560);   // Q frag order
  unsigned short* kfr    = (unsigned short*)(ws + 79691776);   // K frag order
  unsigned short* vfr    = (unsigned short*)(ws + 83886080);   // V frag order
  unsigned short* yb     = xb;                                 // attn out (B,T,C) bf16 (xb dead)

  cast_bf16_k<<<dim3(8192), dim3(256), 0, stream>>>(x, xb);
  wtrans4<<<dim3(10240), dim3(32, 8), 0, stream>>>(
      Wq, Wk, Wv, Wo,
      Wqkvt, Wqkvt + (size_t)2048 * 2048, Wqkvt + (size_t)2560 * 2048, Wot);
  qkv_gemm2p<<<dim3(256), dim3(512), 0, stream>>>(xb, Wqkvt, qkvcat);
  ropenorm<16><<<dim3(16384), dim3(256), 0, stream>>>(qkvcat, cs, sn, qfr,
                                                      0.08838834764831845f, 3072, 0);
  ropenorm<4><<<dim3(4096),  dim3(256), 0, stream>>>(qkvcat, cs, sn, kfr, 1.0f, 3072, 2048);
  vfrag_k<<<dim3(32, 8), dim3(128, 2), 0, stream>>>(qkvcat, vfr);
  attn_kernel<<<dim3(8, 32), dim3(512), 0, stream>>>(qfr, kfr, vfr, yb);
  out_gemm<<<dim3(16, 32), dim3(256), 0, stream>>>(yb, Wot, out);
}

// Round 7
// 282.123 us; speedup vs baseline: 1.1466x; 1.0427x over previous
//
#include <hip/hip_runtime.h>

using bf16x8 = __attribute__((ext_vector_type(8))) short;
using f32x4  = __attribute__((ext_vector_type(4))) float;

#define B_  2
#define T_  2048
#define C_  2048
#define H_  16
#define KV_ 4
#define D_  128

__device__ __forceinline__ unsigned short f2b(float f) {
  union { float f; unsigned int u; } v; v.f = f;
  unsigned int r = v.u + 0x7fffu + ((v.u >> 16) & 1u);   // RTNE
  return (unsigned short)(r >> 16);
}
__device__ __forceinline__ float b2f(unsigned short u) {
  union { unsigned int u; float f; } v; v.u = ((unsigned int)u) << 16;
  return v.f;
}
// packed f32x2 -> bf16x2 (RTNE), single VALU op (no gfx950 builtin; T12 recipe)
__device__ __forceinline__ unsigned int cvt_pk_bf16(float lo, float hi) {
  unsigned int r;
  asm("v_cvt_pk_bf16_f32 %0, %1, %2" : "=v"(r) : "v"(lo), "v"(hi));
  return r;
}
// async global->LDS, 16B per lane; LDS dest must be lane-contiguous (wave base + lane*16)
__device__ __forceinline__ void gld_lds16(const void* g, void* l) {
  __builtin_amdgcn_global_load_lds(
      (__attribute__((address_space(1))) void*)g,
      (__attribute__((address_space(3))) void*)l, 16, 0, 0);
}

// ------------- prep: x cast (8192 blocks) + 4x weight transpose (10240 blocks) -------------
// One launch instead of two (saves a gap); both paths use 256 threads.
__global__ void prep(const float* __restrict__ x, unsigned short* __restrict__ xb,
                     const float* __restrict__ Wq, const float* __restrict__ Wk,
                     const float* __restrict__ Wv, const float* __restrict__ Wo,
                     unsigned short* __restrict__ Wqt, unsigned short* __restrict__ Wkt,
                     unsigned short* __restrict__ Wvt, unsigned short* __restrict__ Wot) {
  __shared__ float s[32][33];
  int bid = blockIdx.x, tid = threadIdx.x;
  if (bid < 8192) {                          // cast x -> bf16
    int i = bid * 256 + tid;
    float4 f = ((const float4*)x)[i];
    ushort4 u; u.x = f2b(f.x); u.y = f2b(f.y); u.z = f2b(f.z); u.w = f2b(f.w);
    ((ushort4*)xb)[i] = u;
    return;
  }
  int id = bid - 8192;
  const float* W; unsigned short* Wt; int N;
  if (id < 4096)      { W = Wq; Wt = Wqt; N = 2048; }
  else if (id < 5120) { W = Wk; Wt = Wkt; N = 512;  id -= 4096; }
  else if (id < 6144) { W = Wv; Wt = Wvt; N = 512;  id -= 5120; }
  else                { W = Wo; Wt = Wot; N = 2048; id -= 6144; }
  int ntiles = N >> 5;
  int n0 = (id % ntiles) * 32, k0 = (id / ntiles) * 32;
  int tx = tid & 31, ty = tid >> 5;
  #pragma unroll
  for (int yy = 0; yy < 32; yy += 8)
    s[ty + yy][tx] = W[(size_t)(k0 + ty + yy) * N + n0 + tx];
  __syncthreads();
  #pragma unroll
  for (int yy = 0; yy < 32; yy += 8)
    Wt[(size_t)(n0 + ty + yy) * 2048 + k0 + tx] = f2b(s[tx][ty + yy]);
}

// ------------- qkv GEMM: fused-N 256x192 tile, compiler-scheduled 2-phase -------------
// (verified 59us / 873 TF: plain ds_reads, compiler-scheduled; 256-block exact CU fill.)
__global__ __launch_bounds__(512, 2) void qkv_gemm2p(
    const unsigned short* __restrict__ xb,
    const unsigned short* __restrict__ Wt,      // 3072 x 2048 (Q|K|V rows)
    unsigned short* __restrict__ qkv) {         // 4096 x 3072
  __shared__ unsigned short lds[57344];         // A: 32768 sh ; B at +32768: 24576 sh

  const int id  = (int)blockIdx.x;              // 0..255; id&7 = XCD (round-robin)
  const int xcd = id & 7, j = id >> 3;          // 32 blocks per XCD
  const int mt  = xcd * 2 + (j >> 4);           // each XCD owns 2 A-panels (L2-resident)
  const int nt  = j & 15;
  const int m0 = mt * 256, n0 = nt * 192;

  const int tid = (int)threadIdx.x;
  const int w = tid >> 6, lane = tid & 63;
  const int quad = lane >> 4, l16 = lane & 15;
  const int wr = w >> 1, wc = w & 1;            // wave tile: rows wr*64, cols wc*96
  const int swz = (l16 & 12) << 1;              // ((row>>2)&3)<<3 in shorts

  const unsigned short* Ab = xb + (size_t)m0 * 2048;
  const unsigned short* Bb = Wt + (size_t)n0 * 2048;

  int ar[4], axc[4];
  #pragma unroll
  for (int kq = 0; kq < 4; ++kq) {
    int ca = tid + kq * 512;
    ar[kq]  = (ca & 1023) >> 2;
    axc[kq] = ((ca & 3) * 8) ^ ((((ca & 1023) >> 4) & 3) << 3);   // inverse-swizzled src col
  }
  const int khb1 = (tid < 256) ? 0 : 1;
  int bidx[3] = { tid, tid + 512 - khb1 * 768, tid + 256 };
  int bkh[3]  = { 0, khb1, 1 };
  int br[3], bxc[3];
  #pragma unroll
  for (int kq = 0; kq < 3; ++kq) {
    br[kq]  = bidx[kq] >> 2;
    bxc[kq] = ((bidx[kq] & 3) * 8) ^ (((bidx[kq] >> 4) & 3) << 3);
  }

#define STAGE(buf, kb) do { \
    unsigned short* da_ = lds + (buf) * 16384; \
    _Pragma("unroll") \
    for (int kq = 0; kq < 4; ++kq) { \
      int ca_ = tid + kq * 512; \
      gld_lds16(Ab + (size_t)ar[kq] * 2048 + (kb) + (ca_ >> 10) * 32 + axc[kq], da_ + ca_ * 8); \
    } \
    unsigned short* db_ = lds + 32768 + (buf) * 12288; \
    _Pragma("unroll") \
    for (int kq = 0; kq < 3; ++kq) \
      gld_lds16(Bb + (size_t)br[kq] * 2048 + (kb) + bkh[kq] * 32 + bxc[kq], \
                db_ + bkh[kq] * 6144 + bidx[kq] * 8); \
  } while (0)

  f32x4 acc[4][6] = {};

  STAGE(0, 0);
  __syncthreads();

  const unsigned short* aB = lds + (wr * 64 + l16) * 32 + (quad * 8 ^ swz);
  const unsigned short* bB = lds + 32768 + (wc * 96 + l16) * 32 + (quad * 8 ^ swz);

  for (int t = 0; t < 32; ++t) {
    const int cur = t & 1;
    if (t < 31) STAGE(cur ^ 1, (t + 1) * 64);   // issue first; reads+MFMA hide it
    #pragma unroll
    for (int kh = 0; kh < 2; ++kh) {
      bf16x8 a[4], b[6];
      #pragma unroll
      for (int m = 0; m < 4; ++m)
        a[m] = *(const bf16x8*)(aB + cur * 16384 + kh * 8192 + m * 512);
      #pragma unroll
      for (int n = 0; n < 6; ++n)
        b[n] = *(const bf16x8*)(bB + cur * 12288 + kh * 6144 + n * 512);
      #pragma unroll
      for (int m = 0; m < 4; ++m)
        #pragma unroll
        for (int n = 0; n < 6; ++n)
          acc[m][n] = __builtin_amdgcn_mfma_f32_16x16x32_bf16(a[m], b[n], acc[m][n], 0, 0, 0);
    }
    __syncthreads();    // vmcnt(0)+lgkm(0)+barrier: stage had full-iter lead -> cheap
  }
#undef STAGE

  #pragma unroll
  for (int m = 0; m < 4; ++m)
    #pragma unroll
    for (int r = 0; r < 4; ++r) {
      int row = m0 + wr * 64 + m * 16 + quad * 4 + r;
      #pragma unroll
      for (int n = 0; n < 6; ++n) {
        int col = n0 + wc * 96 + n * 16 + l16;
        qkv[(size_t)row * 3072 + col] = f2b(acc[m][n][r]);
      }
    }
}

// ------------- out GEMM v2: 256x128 tile, same proven 2-phase structure -------------
// Port of the v10 qkv structure (70.8->59us there): BM=256 BN=128 BK=64, 8 waves 4Mx2N
// (wave 64x64), 256 blocks = 16mt x 16nt exact CU fill, XCD-striped, LDS 48KB double-buf,
// same verified XOR swizzle (inverse on global source). Output fp32 direct.
__global__ __launch_bounds__(512, 2) void out_gemm2p(
    const unsigned short* __restrict__ yb,      // 4096 x 2048 bf16
    const unsigned short* __restrict__ Wot,     // 2048 x 2048 bf16 (N x K)
    float* __restrict__ out) {                  // 4096 x 2048 fp32
  __shared__ unsigned short lds[49152];         // A: 32768 sh ; B at +32768: 16384 sh

  const int id  = (int)blockIdx.x;              // 0..255
  const int xcd = id & 7, j = id >> 3;
  const int mt  = xcd * 2 + (j >> 4);
  const int nt  = j & 15;
  const int m0 = mt * 256, n0 = nt * 128;

  const int tid = (int)threadIdx.x;
  const int w = tid >> 6, lane = tid & 63;
  const int quad = lane >> 4, l16 = lane & 15;
  const int wr = w >> 1, wc = w & 1;            // wave tile: rows wr*64, cols wc*64
  const int swz = (l16 & 12) << 1;

  const unsigned short* Ab = yb  + (size_t)m0 * 2048;
  const unsigned short* Bb = Wot + (size_t)n0 * 2048;

  int ar[4], axc[4];                            // A: 2048 chunks, 4/thread
  #pragma unroll
  for (int kq = 0; kq < 4; ++kq) {
    int ca = tid + kq * 512;
    ar[kq]  = (ca & 1023) >> 2;
    axc[kq] = ((ca & 3) * 8) ^ ((((ca & 1023) >> 4) & 3) << 3);
  }
  int brr[2], bxc[2];                           // B: 1024 chunks, 2/thread (kh = kq)
  #pragma unroll
  for (int kq = 0; kq < 2; ++kq) {
    int cb = tid + kq * 512;
    brr[kq] = (cb & 511) >> 2;
    bxc[kq] = ((cb & 3) * 8) ^ ((((cb & 511) >> 4) & 3) << 3);
  }

#define STAGE(buf, kb) do { \
    unsigned short* da_ = lds + (buf) * 16384; \
    _Pragma("unroll") \
    for (int kq = 0; kq < 4; ++kq) { \
      int ca_ = tid + kq * 512; \
      gld_lds16(Ab + (size_t)ar[kq] * 2048 + (kb) + (ca_ >> 10) * 32 + axc[kq], da_ + ca_ * 8); \
    } \
    unsigned short* db_ = lds + 32768 + (buf) * 8192; \
    _Pragma("unroll") \
    for (int kq = 0; kq < 2; ++kq) { \
      int cb_ = tid + kq * 512; \
      gld_lds16(Bb + (size_t)brr[kq] * 2048 + (kb) + kq * 32 + bxc[kq], db_ + cb_ * 8); \
    } \
  } while (0)

  f32x4 acc[4][4] = {};

  STAGE(0, 0);
  __syncthreads();

  const unsigned short* aB = lds + (wr * 64 + l16) * 32 + (quad * 8 ^ swz);
  const unsigned short* bB = lds + 32768 + (wc * 64 + l16) * 32 + (quad * 8 ^ swz);

  for (int t = 0; t < 32; ++t) {
    const int cur = t & 1;
    if (t < 31) STAGE(cur ^ 1, (t + 1) * 64);
    #pragma unroll
    for (int kh = 0; kh < 2; ++kh) {
      bf16x8 a[4], b[4];
      #pragma unroll
      for (int m = 0; m < 4; ++m)
        a[m] = *(const bf16x8*)(aB + cur * 16384 + kh * 8192 + m * 512);
      #pragma unroll
      for (int n = 0; n < 4; ++n)
        b[n] = *(const bf16x8*)(bB + cur * 8192 + kh * 4096 + n * 512);
      #pragma unroll
      for (int m = 0; m < 4; ++m)
        #pragma unroll
        for (int n = 0; n < 4; ++n)
          acc[m][n] = __builtin_amdgcn_mfma_f32_16x16x32_bf16(a[m], b[n], acc[m][n], 0, 0, 0);
    }
    __syncthreads();
  }
#undef STAGE

  #pragma unroll
  for (int m = 0; m < 4; ++m)
    #pragma unroll
    for (int r = 0; r < 4; ++r) {
      int row = m0 + wr * 64 + m * 16 + quad * 4 + r;
      #pragma unroll
      for (int n = 0; n < 4; ++n) {
        int col = n0 + wc * 64 + n * 16 + l16;
        out[(size_t)row * 2048 + col] = acc[m][n][r];
      }
    }
}

// ---------------- RoPE + RMSNorm (Q and K fused in one launch) ----------------
// Lane loads one uint (2 adjacent bf16); RoPE partner via shfl_xor(32); packed store.
// per (b,head): [t16 (128 tiles)][f = d>>3 (16)][t&15 (16)][d&7 (8)]  (tile = 2048 shorts)
template <int NH>
__device__ __forceinline__ void ropenorm_row(
    const unsigned short* __restrict__ in, const float* __restrict__ cs,
    const float* __restrict__ sn, unsigned short* __restrict__ out,
    float oscale, int off, int row, int lane) {
  int head = row % NH;
  int t = (row / NH) & (T_ - 1);
  int b = row / (NH * T_);
  const unsigned short* p = in + (size_t)(b * T_ + t) * 3072 + off + head * D_;
  unsigned int u  = *(const unsigned int*)(p + 2 * lane);
  unsigned int up = (unsigned int)__shfl_xor((int)u, 32, 64);
  int dh = (lane & 31) * 2;
  float2 c2 = ((const float2*)(cs + t * 64))[lane & 31];
  float2 s2 = ((const float2*)(sn + t * 64))[lane & 31];
  float a0 = b2f((unsigned short)(u & 0xffff)),  a1 = b2f((unsigned short)(u >> 16));
  float p0 = b2f((unsigned short)(up & 0xffff)), p1 = b2f((unsigned short)(up >> 16));
  float sgn = (lane < 32) ? 1.0f : -1.0f;
  float oa = a0 * c2.x + sgn * p0 * s2.x;
  float ob = a1 * c2.y + sgn * p1 * s2.y;
  float ss = oa * oa + ob * ob;
  #pragma unroll
  for (int off2 = 32; off2 > 0; off2 >>= 1) ss += __shfl_xor(ss, off2, 64);
  float r = rsqrtf(ss * (1.0f / 128.0f) + 1.1920929e-07f) * oscale;
  unsigned int outu = cvt_pk_bf16(oa * r, ob * r);
  size_t base = ((size_t)((b * NH + head) * 128 + (t >> 4))) * 2048 + (size_t)(t & 15) * 8;
  int f = ((lane < 32) ? 0 : 8) + (dh >> 3);
  *(unsigned int*)(out + base + (size_t)f * 128 + (dh & 7)) = outu;
}

__global__ void ropenorm_qk(const unsigned short* __restrict__ qkv,
                            const float* __restrict__ cs, const float* __restrict__ sn,
                            unsigned short* __restrict__ qfr,
                            unsigned short* __restrict__ kfr) {
  int bid = blockIdx.x;
  int lane = threadIdx.x & 63;
  int wv = threadIdx.x >> 6;
  if (bid < 16384) {
    ropenorm_row<16>(qkv, cs, sn, qfr, 0.08838834764831845f, 0, bid * 4 + wv, lane);
  } else {
    ropenorm_row<4>(qkv, cs, sn, kfr, 1.0f, 2048, (bid - 16384) * 4 + wv, lane);
  }
}

// ---------------- V repack: fused qkv (V at col 2560) -> fragment order ---------
// per (b,kv): [it (32 tiles of 64 t)][dt = d>>4 (8)][f = (t&63)>>3 (8)][d&15 (16)][t&7 (8)]
__global__ void vfrag_k(const unsigned short* __restrict__ qkv, unsigned short* __restrict__ vf) {
  int it = blockIdx.x;
  int b = blockIdx.y >> 2, kv = blockIdx.y & 3;
  int d = threadIdx.x, ty = threadIdx.y;
  int t0 = it * 64;
  size_t obase = ((size_t)((b * KV_ + kv) * 32 + it)) * 8192
               + (size_t)(d >> 4) * 1024 + (size_t)(d & 15) * 8;
  #pragma unroll
  for (int tcg = 0; tcg < 4; ++tcg) {
    int tc = ty * 4 + tcg;                   // f chunk 0..7
    unsigned short val[8];
    #pragma unroll
    for (int e = 0; e < 8; ++e)              // coalesced: 128 lanes contiguous in d
      val[e] = qkv[((size_t)(b * T_) + t0 + tc * 8 + e) * 3072 + 2560 + kv * D_ + d];
    ushort4 u0 = {val[0], val[1], val[2], val[3]};
    ushort4 u1 = {val[4], val[5], val[6], val[7]};
    *(ushort4*)(vf + obase + (size_t)tc * 128)     = u0;
    *(ushort4*)(vf + obase + (size_t)tc * 128 + 4) = u1;
  }
}

// ------------ flash attention v11: head-shared LDS K/V staging, uniform blocks ------------
// (verified R6: dropped below 59us.) Block = 8 waves = 4 heads x 2 kv-halves; qt = j then
// 63-j; K/V staged once per kv-group via global_load_lds (L2 traffic /4); counted vmcnt;
// XOR-swizzled K/V reads; static max M=12 -> halves combine linearly.
__global__ __launch_bounds__(512, 2) void attn_kernel(
    const unsigned short* __restrict__ qf, const unsigned short* __restrict__ kf,
    const unsigned short* __restrict__ vf, unsigned short* __restrict__ yb) {
  __shared__ __align__(16) char smem[135168];
  unsigned short* kls = (unsigned short*)smem;            // [2 buf][2 slot][8192 sh]
  unsigned short* vls = (unsigned short*)(smem + 65536);  // [2 slot][8192 sh]
  unsigned short* Pls = (unsigned short*)(smem + 98304);  // 8 waves x 32x72 sh

  const int xp = (int)blockIdx.x, b = xp >> 2, kv = xp & 3;   // XCD swizzle: id%8 = xp
  const int jy = (int)blockIdx.y;                             // 0..31
  const int tid = (int)threadIdx.x;
  const int w = tid >> 6, lane = tid & 63;
  const int quad = lane >> 4, l16 = lane & 15;
  const int hh = w & 3, half = w >> 2;
  const int h = kv * 4 + hh;
  unsigned short* myP = Pls + w * (32 * 72);

  const unsigned short* Kf = kf + (size_t)(b * KV_ + kv) * 128 * 2048;
  const unsigned short* Vf = vf + (size_t)(b * KV_ + kv) * 32 * 8192;

  const int swl = quad << 4;                 // swizzle key (shorts): chunk ^ (quad<<1)
  const int cs0 = (tid * 8) ^ swl;           // staging source offsets within a 16KB tile
  const int cs1 = ((tid + 512) * 8) ^ swl;
  const int cd0 = tid * 8, cd1 = tid * 8 + 4096;   // linear LDS dest (lane-contiguous)

#define STAGE_K(buf, it0) do { \
    const unsigned short* s_ = Kf + (size_t)(it0) * 8192; \
    unsigned short* d_ = kls + (buf) * 16384; \
    gld_lds16(s_ + cs0, d_ + cd0);               gld_lds16(s_ + cs1, d_ + cd1); \
    gld_lds16(s_ + 8192 + cs0, d_ + 8192 + cd0); gld_lds16(s_ + 8192 + cs1, d_ + 8192 + cd1); \
  } while (0)
#define STAGE_V(it0) do { \
    const unsigned short* s_ = Vf + (size_t)(it0) * 8192; \
    gld_lds16(s_ + cs0, vls + cd0);               gld_lds16(s_ + cs1, vls + cd1); \
    gld_lds16(s_ + 8192 + cs0, vls + 8192 + cd0); gld_lds16(s_ + 8192 + cs1, vls + 8192 + cd1); \
  } while (0)

  for (int ph = 0; ph < 2; ++ph) {
    const int qt = ph ? (63 - jy) : jy;
    const int q0 = qt * 32;
    const int ntile = (qt >> 1) + 1;
    const int R = (ntile + 1) >> 1;

    const unsigned short* Qf = qf + ((size_t)(b * H_ + h) * 128 + qt * 2) * 2048;
    bf16x8 bq[2][4];
    #pragma unroll
    for (int i = 0; i < 2; ++i)
      #pragma unroll
      for (int kk = 0; kk < 4; ++kk)
        bq[i][kk] = *(const bf16x8*)(Qf + (size_t)i * 2048 + (kk * 4 + quad) * 128 + l16 * 8);

    float l_i[2] = {0.f, 0.f};
    f32x4 o[2][8] = {};

    STAGE_K(0, 0);                           // prologue: K tiles 0,1 -> buf 0

    for (int r = 0; r < R; ++r) {
      const int cur = r & 1;
      const bool more = (r + 1 < R);
      STAGE_V(2 * r);
      if (more) STAGE_K(cur ^ 1, 2 * r + 2);
      if (more) asm volatile("s_waitcnt vmcnt(8)" ::: "memory");  // K(2r,2r+1) landed (own)
      else      asm volatile("s_waitcnt vmcnt(4)" ::: "memory");
      __builtin_amdgcn_s_barrier();                               // ...and globally

      const int it = 2 * r + half;
      const bool active = it < ntile;        // wave-uniform
      f32x4 sc[4][2] = {};
      if (active) {
        const unsigned short* kb = kls + cur * 16384 + half * 8192;
        #pragma unroll
        for (int kk = 0; kk < 4; ++kk) {
          bf16x8 ak[4];
          #pragma unroll
          for (int jt = 0; jt < 4; ++jt)
            ak[jt] = *(const bf16x8*)(kb + ((jt * 2048 + (kk * 4 + quad) * 128 + l16 * 8) ^ swl));
          #pragma unroll
          for (int jt = 0; jt < 4; ++jt)
            #pragma unroll
            for (int i = 0; i < 2; ++i)
              sc[jt][i] = __builtin_amdgcn_mfma_f32_16x16x32_bf16(ak[jt], bq[i][kk], sc[jt][i], 0, 0, 0);
        }
        if (it == ntile - 1) {               // causal mask on the diagonal tile
          #pragma unroll
          for (int jt = 0; jt < 4; ++jt) {
            int kg = it * 64 + jt * 16 + quad * 4;
            #pragma unroll
            for (int i = 0; i < 2; ++i) {
              int qg = q0 + i * 16 + l16;
              #pragma unroll
              for (int rr = 0; rr < 4; ++rr)
                if (kg + rr > qg) sc[jt][i][rr] = -3.0e38f;
            }
          }
        }
        #pragma unroll
        for (int i = 0; i < 2; ++i) {
          float part = 0.f;
          #pragma unroll
          for (int jt = 0; jt < 4; ++jt)
            #pragma unroll
            for (int rr = 0; rr < 4; ++rr) {
              float p = __expf(sc[jt][i][rr] - 12.0f);
              sc[jt][i][rr] = p; part += p;
            }
          l_i[i] += part;
        }
        #pragma unroll
        for (int i = 0; i < 2; ++i)
          #pragma unroll
          for (int jt = 0; jt < 4; ++jt) {
            uint2 uu;
            uu.x = cvt_pk_bf16(sc[jt][i][0], sc[jt][i][1]);
            uu.y = cvt_pk_bf16(sc[jt][i][2], sc[jt][i][3]);
            *(uint2*)(myP + (i * 16 + l16) * 72 + jt * 16 + quad * 4) = uu;
          }
      }

      if (more) asm volatile("s_waitcnt vmcnt(4)" ::: "memory");  // V(2r,2r+1) landed
      else      asm volatile("s_waitcnt vmcnt(0)" ::: "memory");
      __builtin_amdgcn_s_barrier();

      if (active) {
        const unsigned short* vb = vls + half * 8192;
        #pragma unroll
        for (int kk2 = 0; kk2 < 2; ++kk2) {
          bf16x8 ap[2], bv2[8];
          #pragma unroll
          for (int i = 0; i < 2; ++i)
            ap[i] = *(const bf16x8*)(myP + (i * 16 + l16) * 72 + kk2 * 32 + quad * 8);
          #pragma unroll
          for (int jj = 0; jj < 8; ++jj)
            bv2[jj] = *(const bf16x8*)(vb + ((jj * 1024 + (kk2 * 4 + quad) * 128 + l16 * 8) ^ swl));
          #pragma unroll
          for (int i = 0; i < 2; ++i)
            #pragma unroll
            for (int jj = 0; jj < 8; ++jj)
              o[i][jj] = __builtin_amdgcn_mfma_f32_16x16x32_bf16(ap[i], bv2[jj], o[i][jj], 0, 0, 0);
        }
      }
      __builtin_amdgcn_s_barrier();          // all PV reads done before next STAGE_V
    }

    float lsum[2];
    #pragma unroll
    for (int i = 0; i < 2; ++i) {
      float l = l_i[i];
      l += __shfl_xor(l, 16, 64);
      l += __shfl_xor(l, 32, 64);
      lsum[i] = l;
    }

    __syncthreads();                         // rounds done; kls/vls dead -> combine scratch
    float* oc = (float*)smem + hh * 4256;    // per head: 32x132 o + 32 l floats
    float* lc = oc + 32 * 132;
    if (half == 1) {
      #pragma unroll
      for (int i = 0; i < 2; ++i) {
        if (quad == 0) lc[i * 16 + l16] = lsum[i];
        #pragma unroll
        for (int jj = 0; jj < 8; ++jj)
          #pragma unroll
          for (int rr = 0; rr < 4; ++rr)
            oc[(i * 16 + quad * 4 + rr) * 132 + jj * 16 + l16] = o[i][jj][rr];
      }
    }
    __syncthreads();
    if (half == 0) {                         // linear combine (static max) + store
      #pragma unroll
      for (int i = 0; i < 2; ++i) {
        float l = lsum[i] + lc[i * 16 + l16];
        float linv = 1.0f / l;
        float lr[4];
        #pragma unroll
        for (int rr = 0; rr < 4; ++rr) lr[rr] = __shfl(linv, quad * 4 + rr, 64);
        #pragma unroll
        for (int rr = 0; rr < 4; ++rr) {
          int tg = q0 + i * 16 + quad * 4 + rr;
          unsigned short* yr = yb + (((size_t)(b * T_ + tg)) * H_ + h) * D_;
          #pragma unroll
          for (int jj = 0; jj < 8; ++jj) {
            float vsum = o[i][jj][rr] + oc[(i * 16 + quad * 4 + rr) * 132 + jj * 16 + l16];
            yr[jj * 16 + l16] = f2b(vsum * lr[rr]);
          }
        }
      }
    }
    __syncthreads();                         // scratch reads done before next phase stages
  }
#undef STAGE_K
#undef STAGE_V
}

extern "C" void kernel_launch(void* const* d_in, const int* in_sizes, int n_in,
                              void* d_out, int out_size, void* d_ws, size_t ws_size,
                              hipStream_t stream) {
  (void)in_sizes; (void)n_in; (void)out_size; (void)ws_size;
  const float* x  = (const float*)d_in[0];
  const float* cs = (const float*)d_in[1];
  const float* sn = (const float*)d_in[2];
  const float* Wq = (const float*)d_in[3];
  const float* Wk = (const float*)d_in[4];
  const float* Wv = (const float*)d_in[5];
  const float* Wo = (const float*)d_in[6];
  float* out = (float*)d_out;
  char* ws = (char*)d_ws;

  // workspace layout (bytes); regions reused across phases. total ~88MB.
  unsigned short* xb     = (unsigned short*)(ws + 0);          // 4096x2048 bf16 (dead after qkv)
  unsigned short* Wqkvt  = (unsigned short*)(ws + 16777216);   // 3072x2048 bf16 (dead after qkv)
  unsigned short* Wot    = (unsigned short*)(ws + 29360128);   // needed until out_gemm
  unsigned short* qkvcat = (unsigned short*)(ws + 37748736);   // 4096x3072 bf16 fused Q|K|V
  unsigned short* qfr    = (unsigned short*)(ws + 62914560);   // Q frag order
  unsigned short* kfr    = (unsigned short*)(ws + 79691776);   // K frag order
  unsigned short* vfr    = (unsigned short*)(ws + 83886080);   // V frag order
  unsigned short* yb     = xb;                                 // attn out (B,T,C) bf16 (xb dead)

  prep<<<dim3(18432), dim3(256), 0, stream>>>(
      x, xb, Wq, Wk, Wv, Wo,
      Wqkvt, Wqkvt + (size_t)2048 * 2048, Wqkvt + (size_t)2560 * 2048, Wot);
  qkv_gemm2p<<<dim3(256), dim3(512), 0, stream>>>(xb, Wqkvt, qkvcat);
  ropenorm_qk<<<dim3(20480), dim3(256), 0, stream>>>(qkvcat, cs, sn, qfr, kfr);
  vfrag_k<<<dim3(32, 8), dim3(128, 2), 0, stream>>>(qkvcat, vfr);
  attn_kernel<<<dim3(8, 32), dim3(512), 0, stream>>>(qfr, kfr, vfr, yb);
  out_gemm2p<<<dim3(256), dim3(512), 0, stream>>>(yb, Wot, out);
}